// Round 2
// baseline (3396.086 us; speedup 1.0000x reference)
//
#include <hip/hip_runtime.h>
#include <math.h>

// Problem constants (fixed by the reference's setup_inputs)
#define NU 100000
#define NI 50000
#define NN 150000          // NU + NI
#define NB 4096            // batch of (user,item) pairs
#define LNEPS 1e-5f

// ---------------------------------------------------------------------------
// Phase A: degree + symmetric norm per edge
// ---------------------------------------------------------------------------
__global__ __launch_bounds__(256) void k_deg(const int* __restrict__ row,
                                             float* __restrict__ deg, int E) {
    int e = blockIdx.x * 256 + threadIdx.x;
    if (e < E) atomicAdd(&deg[row[e]], 1.0f);
}

__global__ __launch_bounds__(256) void k_norm(const int* __restrict__ row,
                                              const int* __restrict__ col,
                                              const float* __restrict__ deg,
                                              float* __restrict__ nrm, int E) {
    int e = blockIdx.x * 256 + threadIdx.x;
    if (e < E) nrm[e] = rsqrtf(deg[row[e]]) * rsqrtf(deg[col[e]]);
}

// Mark sampled nodes S (bitmap), then R = {row : edge row->col with col in S}.
__global__ __launch_bounds__(256) void k_markS(const int* __restrict__ users,
                                               const int* __restrict__ items,
                                               unsigned* __restrict__ bS, int nb) {
    int t = blockIdx.x * 256 + threadIdx.x;
    if (t < 2 * nb) {
        int node = (t < nb) ? users[t] : (NU + items[t - nb]);
        atomicOr(&bS[node >> 5], 1u << (node & 31));
    }
}

__global__ __launch_bounds__(256) void k_markR(const int* __restrict__ row,
                                               const int* __restrict__ col,
                                               const unsigned* __restrict__ bS,
                                               unsigned* __restrict__ bR, int E) {
    int e = blockIdx.x * 256 + threadIdx.x;
    if (e < E) {
        int c = col[e];
        if ((bS[c >> 5] >> (c & 31)) & 1u) {
            int r = row[e];
            atomicOr(&bR[r >> 5], 1u << (r & 31));
        }
    }
}

// ---------------------------------------------------------------------------
// h = X @ W (64x64) + b.  16 rows/block, 256 threads (4 rows/thread).
// X == nullptr means "concat(user_table, item_table)".
// ---------------------------------------------------------------------------
__global__ __launch_bounds__(256) void k_gemm64(const float* __restrict__ X,
                                                const float* __restrict__ ut,
                                                const float* __restrict__ itb,
                                                const float* __restrict__ W,
                                                const float* __restrict__ bias,
                                                float* __restrict__ Y, int nRows) {
    __shared__ float Ws[4096];
    __shared__ float xsh[16][64];
    int tid = threadIdx.x, j = tid & 63, rq = tid >> 6;
    for (int i = tid; i < 4096; i += 256) Ws[i] = W[i];
    int r0 = blockIdx.x * 16;
    for (int i = tid; i < 1024; i += 256) {
        int rr = i >> 6, kk = i & 63;
        int r = r0 + rr;
        float v = 0.f;
        if (r < nRows) {
            v = X ? X[(size_t)r * 64 + kk]
                  : (r < NU ? ut[(size_t)r * 64 + kk]
                            : itb[(size_t)(r - NU) * 64 + kk]);
        }
        xsh[rr][kk] = v;
    }
    __syncthreads();
    float acc[4];
#pragma unroll
    for (int i = 0; i < 4; ++i) acc[i] = bias[j];
    for (int k = 0; k < 64; ++k) {
        float w = Ws[k * 64 + j];
#pragma unroll
        for (int i = 0; i < 4; ++i) acc[i] = fmaf(xsh[rq + 4 * i][k], w, acc[i]);
    }
#pragma unroll
    for (int i = 0; i < 4; ++i) {
        int r = r0 + rq + 4 * i;
        if (r < nRows) Y[(size_t)r * 64 + j] = acc[i];
    }
}

// ---------------------------------------------------------------------------
// Edge scatter: Xo[col] += nrm * H[row], filtered by bitmap on col.
// 16 threads per edge, float4 each.
// ---------------------------------------------------------------------------
__global__ __launch_bounds__(256) void k_scatter(const int* __restrict__ row,
                                                 const int* __restrict__ col,
                                                 const float* __restrict__ nrm,
                                                 const float* __restrict__ H,
                                                 const unsigned* __restrict__ filt,
                                                 float* __restrict__ Xo, int E) {
    long long t = (long long)blockIdx.x * 256 + threadIdx.x;
    int e = (int)(t >> 4);
    if (e >= E) return;
    int c = col[e];
    if (!((filt[c >> 5] >> (c & 31)) & 1u)) return;
    int q = (int)(t & 15) * 4;
    int r = row[e];
    float nv = nrm[e];
    const float4 h = *reinterpret_cast<const float4*>(H + (size_t)r * 64 + q);
    float* xp = Xo + (size_t)c * 64 + q;
    atomicAdd(xp + 0, nv * h.x);
    atomicAdd(xp + 1, nv * h.y);
    atomicAdd(xp + 2, nv * h.z);
    atomicAdd(xp + 3, nv * h.w);
}

// ---------------------------------------------------------------------------
// Gather sampled rows + corr projection: Cb[b] = X2[node(b)] @ corrW + corrB
// rows 0..NB-1 = users, NB..2NB-1 = items.
// ---------------------------------------------------------------------------
__global__ __launch_bounds__(256) void k_corr(const float* __restrict__ X2,
                                              const int* __restrict__ users,
                                              const int* __restrict__ items,
                                              const float* __restrict__ W,
                                              const float* __restrict__ bias,
                                              float* __restrict__ Cb, int nb) {
    __shared__ float Ws[4096];
    __shared__ float xsh[16][64];
    int tid = threadIdx.x, j = tid & 63, rq = tid >> 6;
    for (int i = tid; i < 4096; i += 256) Ws[i] = W[i];
    int r0 = blockIdx.x * 16;
    for (int i = tid; i < 1024; i += 256) {
        int b = r0 + (i >> 6), kk = i & 63;
        int node = (b < nb) ? users[b] : (NU + items[b - nb]);
        xsh[i >> 6][kk] = X2[(size_t)node * 64 + kk];
    }
    __syncthreads();
    float acc[4];
#pragma unroll
    for (int i = 0; i < 4; ++i) acc[i] = bias[j];
    for (int k = 0; k < 64; ++k) {
        float w = Ws[k * 64 + j];
#pragma unroll
        for (int i = 0; i < 4; ++i) acc[i] = fmaf(xsh[rq + 4 * i][k], w, acc[i]);
    }
#pragma unroll
    for (int i = 0; i < 4; ++i) Cb[(size_t)(r0 + rq + 4 * i) * 64 + j] = acc[i];
}

// ---------------------------------------------------------------------------
// Per-row transformer (V-proj -> out-proj -> LN -> FFN -> LN) x 2 layers.
// 16 rows/block, 256 threads; one wave owns a set of 4 rows -> LN reductions
// are 64-lane shuffle reduces.
// ---------------------------------------------------------------------------
__global__ __launch_bounds__(256) void k_tf(float* __restrict__ Cb,
                                            const float* __restrict__ qkvW,
                                            const float* __restrict__ qkvB,
                                            const float* __restrict__ outW,
                                            const float* __restrict__ outB,
                                            const float* __restrict__ ff1W,
                                            const float* __restrict__ ff1B,
                                            const float* __restrict__ ff2W,
                                            const float* __restrict__ ff2B,
                                            const float* __restrict__ ln1g,
                                            const float* __restrict__ ln1b,
                                            const float* __restrict__ ln2g,
                                            const float* __restrict__ ln2b) {
    __shared__ float xs[16][64];
    __shared__ float vs[16][64];
    __shared__ float ts[16][128];
    int tid = threadIdx.x;
    int j = tid & 63, rq = tid >> 6;
    int row0 = blockIdx.x * 16;
    for (int i = tid; i < 1024; i += 256)
        xs[i >> 6][i & 63] = Cb[(size_t)(row0 + (i >> 6)) * 64 + (i & 63)];
    __syncthreads();
    float xcur[4];
#pragma unroll
    for (int i = 0; i < 4; ++i) xcur[i] = xs[rq + 4 * i][j];

    for (int l = 0; l < 2; ++l) {
        const float* Wv = qkvW + l * 64 * 192 + 128;  // V slice of qkv_W
        const float* Wo = outW + l * 64 * 64;
        // --- v = x @ Wv + bv ---
        float bvj = qkvB[l * 192 + 128 + j];
        float va[4];
#pragma unroll
        for (int i = 0; i < 4; ++i) va[i] = bvj;
        for (int k = 0; k < 64; ++k) {
            float w = Wv[k * 192 + j];
#pragma unroll
            for (int i = 0; i < 4; ++i) va[i] = fmaf(xs[rq + 4 * i][k], w, va[i]);
        }
#pragma unroll
        for (int i = 0; i < 4; ++i) vs[rq + 4 * i][j] = va[i];
        __syncthreads();
        // --- attn = v @ Wo + bo ---
        float boj = outB[l * 64 + j];
        float aa[4];
#pragma unroll
        for (int i = 0; i < 4; ++i) aa[i] = boj;
        for (int k = 0; k < 64; ++k) {
            float w = Wo[k * 64 + j];
#pragma unroll
            for (int i = 0; i < 4; ++i) aa[i] = fmaf(vs[rq + 4 * i][k], w, aa[i]);
        }
        // --- x = LN1(x + attn) ---
        float g1 = ln1g[l * 64 + j], b1 = ln1b[l * 64 + j];
#pragma unroll
        for (int i = 0; i < 4; ++i) {
            float xv = xcur[i] + aa[i];
            float s = xv;
#pragma unroll
            for (int o = 32; o >= 1; o >>= 1) s += __shfl_xor(s, o, 64);
            float m = s * (1.0f / 64.0f);
            float d = xv - m;
            float s2 = d * d;
#pragma unroll
            for (int o = 32; o >= 1; o >>= 1) s2 += __shfl_xor(s2, o, 64);
            float xn = d * rsqrtf(s2 * (1.0f / 64.0f) + LNEPS) * g1 + b1;
            xcur[i] = xn;
            xs[rq + 4 * i][j] = xn;
        }
        __syncthreads();
        // --- FFN: y = relu(x@W1+b1)@W2 (+ b2 at the end) ---
        float b2j = ff2B[l * 64 + j];
        float ya[4];
#pragma unroll
        for (int i = 0; i < 4; ++i) ya[i] = 0.f;
        int sub = tid >> 7;    // 0,1
        int ml = tid & 127;
        const float* W1 = ff1W + (size_t)l * 64 * 2048;
        const float* W2 = ff2W + (size_t)l * 2048 * 64;
        const float* B1 = ff1B + l * 2048;
        for (int mc = 0; mc < 2048; mc += 128) {
            float ta[8];
            float bb = B1[mc + ml];
#pragma unroll
            for (int rr = 0; rr < 8; ++rr) ta[rr] = bb;
            for (int k = 0; k < 64; ++k) {
                float w = W1[(size_t)k * 2048 + mc + ml];
#pragma unroll
                for (int rr = 0; rr < 8; ++rr)
                    ta[rr] = fmaf(xs[sub * 8 + rr][k], w, ta[rr]);
            }
#pragma unroll
            for (int rr = 0; rr < 8; ++rr) ts[sub * 8 + rr][ml] = fmaxf(ta[rr], 0.f);
            __syncthreads();
            for (int m = 0; m < 128; ++m) {
                float w2 = W2[(size_t)(mc + m) * 64 + j];
#pragma unroll
                for (int i = 0; i < 4; ++i) ya[i] = fmaf(ts[rq + 4 * i][m], w2, ya[i]);
            }
            __syncthreads();
        }
        // --- x = LN2(x + ffn) ---
        float g2 = ln2g[l * 64 + j], b2 = ln2b[l * 64 + j];
#pragma unroll
        for (int i = 0; i < 4; ++i) {
            float xv = xcur[i] + ya[i] + b2j;
            float s = xv;
#pragma unroll
            for (int o = 32; o >= 1; o >>= 1) s += __shfl_xor(s, o, 64);
            float m = s * (1.0f / 64.0f);
            float d = xv - m;
            float s2 = d * d;
#pragma unroll
            for (int o = 32; o >= 1; o >>= 1) s2 += __shfl_xor(s2, o, 64);
            float xn = d * rsqrtf(s2 * (1.0f / 64.0f) + LNEPS) * g2 + b2;
            xcur[i] = xn;
            xs[rq + 4 * i][j] = xn;
        }
        __syncthreads();
    }
    for (int i = tid; i < 1024; i += 256)
        Cb[(size_t)(row0 + (i >> 6)) * 64 + (i & 63)] = xs[i >> 6][i & 63];
}

// out[b] = dot(user_row b, item_row NB+b); quarter-wave per b.
__global__ __launch_bounds__(256) void k_dot(const float* __restrict__ Cb,
                                             float* __restrict__ out, int nb) {
    int t = blockIdx.x * 256 + threadIdx.x;
    int b = t >> 4;
    if (b >= nb) return;
    int q = (t & 15) * 4;
    const float4 u = *reinterpret_cast<const float4*>(Cb + (size_t)b * 64 + q);
    const float4 v = *reinterpret_cast<const float4*>(Cb + (size_t)(nb + b) * 64 + q);
    float s = u.x * v.x + u.y * v.y + u.z * v.z + u.w * v.w;
#pragma unroll
    for (int o = 8; o >= 1; o >>= 1) s += __shfl_xor(s, o, 16);
    if ((t & 15) == 0) out[b] = s;
}

extern "C" void kernel_launch(void* const* d_in, const int* in_sizes, int n_in,
                              void* d_out, int out_size, void* d_ws, size_t ws_size,
                              hipStream_t stream) {
    const int* users = (const int*)d_in[0];
    const int* items = (const int*)d_in[1];
    const int* ei    = (const int*)d_in[2];
    const float* ut  = (const float*)d_in[3];
    const float* itb = (const float*)d_in[4];
    const float* glW = (const float*)d_in[5];
    const float* glB = (const float*)d_in[6];
    const float* corrW = (const float*)d_in[7];
    const float* corrB = (const float*)d_in[8];
    const float* qkvW = (const float*)d_in[9];
    const float* qkvB = (const float*)d_in[10];
    const float* outW = (const float*)d_in[11];
    const float* outB = (const float*)d_in[12];
    const float* ff1W = (const float*)d_in[13];
    const float* ff1B = (const float*)d_in[14];
    const float* ff2W = (const float*)d_in[15];
    const float* ff2B = (const float*)d_in[16];
    const float* ln1g = (const float*)d_in[17];
    const float* ln1b = (const float*)d_in[18];
    const float* ln2g = (const float*)d_in[19];
    const float* ln2b = (const float*)d_in[20];

    const int E  = in_sizes[2] / 2;      // 1,750,000
    const int nb = in_sizes[0];          // 4096
    const int* rowp = ei;
    const int* colp = ei + E;

    // workspace carve-up (~86 MB)
    char* w = (char*)d_ws;
    size_t off = 0;
    auto alloc = [&](size_t bytes) {
        char* p = w + off;
        off += (bytes + 255) & ~(size_t)255;
        return p;
    };
    float* deg = (float*)alloc((size_t)NN * 4);
    float* nrm = (float*)alloc((size_t)E * 4);
    unsigned* bS = (unsigned*)alloc(((NN + 31) / 32) * 4);
    unsigned* bR = (unsigned*)alloc(((NN + 31) / 32) * 4);
    float* bufA = (float*)alloc((size_t)NN * 64 * 4);
    float* bufB = (float*)alloc((size_t)NN * 64 * 4);
    float* cb   = (float*)alloc((size_t)2 * nb * 64 * 4);
    float* outp = (float*)d_out;

    hipMemsetAsync(deg, 0, (size_t)NN * 4, stream);
    hipMemsetAsync(bS, 0, ((NN + 31) / 32) * 4, stream);
    hipMemsetAsync(bR, 0, ((NN + 31) / 32) * 4, stream);

    int eb = (E + 255) / 256;
    k_deg<<<eb, 256, 0, stream>>>(rowp, deg, E);
    k_norm<<<eb, 256, 0, stream>>>(rowp, colp, deg, nrm, E);
    k_markS<<<(2 * nb + 255) / 256, 256, 0, stream>>>(users, items, bS, nb);
    k_markR<<<eb, 256, 0, stream>>>(rowp, colp, bS, bR, E);

    int gb = (NN + 15) / 16;
    int sb = (int)(((size_t)E * 16 + 255) / 256);

    // GCN layer 0: h = concat(tables)@W0+b0; x1[col in R] += nrm*h[row]
    k_gemm64<<<gb, 256, 0, stream>>>(nullptr, ut, itb, glW, glB, bufA, NN);
    hipMemsetAsync(bufB, 0, (size_t)NN * 64 * 4, stream);
    k_scatter<<<sb, 256, 0, stream>>>(rowp, colp, nrm, bufA, bR, bufB, E);

    // GCN layer 1: h2 = x1@W1+b1; x2[col in S] += nrm*h2[row]
    k_gemm64<<<gb, 256, 0, stream>>>(bufB, ut, itb, glW + 64 * 64, glB + 64, bufA, NN);
    hipMemsetAsync(bufB, 0, (size_t)NN * 64 * 4, stream);
    k_scatter<<<sb, 256, 0, stream>>>(rowp, colp, nrm, bufA, bS, bufB, E);

    // corr projection on the 8192 sampled rows, then per-row transformer
    k_corr<<<(2 * nb + 15) / 16, 256, 0, stream>>>(bufB, users, items, corrW, corrB, cb, nb);
    k_tf<<<(2 * nb + 15) / 16, 256, 0, stream>>>(cb, qkvW, qkvB, outW, outB,
                                                 ff1W, ff1B, ff2W, ff2B,
                                                 ln1g, ln1b, ln2g, ln2b);
    k_dot<<<(nb * 16 + 255) / 256, 256, 0, stream>>>(cb, outp, nb);
}

// Round 3
// 3175.006 us; speedup vs baseline: 1.0696x; 1.0696x over previous
//
#include <hip/hip_runtime.h>
#include <math.h>

// Problem constants (fixed by the reference's setup_inputs)
#define NU 100000
#define NI 50000
#define NN 150000          // NU + NI
#define LNEPS 1e-5f

// ---------------------------------------------------------------------------
// Phase A: degree + symmetric norm per edge
// ---------------------------------------------------------------------------
__global__ __launch_bounds__(256) void k_deg(const int* __restrict__ row,
                                             float* __restrict__ deg, int E) {
    int e = blockIdx.x * 256 + threadIdx.x;
    if (e < E) atomicAdd(&deg[row[e]], 1.0f);
}

__global__ __launch_bounds__(256) void k_norm(const int* __restrict__ row,
                                              const int* __restrict__ col,
                                              const float* __restrict__ deg,
                                              float* __restrict__ nrm, int E) {
    int e = blockIdx.x * 256 + threadIdx.x;
    if (e < E) nrm[e] = rsqrtf(deg[row[e]]) * rsqrtf(deg[col[e]]);
}

// Mark sampled nodes S (bitmap), then R = {row : edge row->col with col in S}.
__global__ __launch_bounds__(256) void k_markS(const int* __restrict__ users,
                                               const int* __restrict__ items,
                                               unsigned* __restrict__ bS, int nb) {
    int t = blockIdx.x * 256 + threadIdx.x;
    if (t < 2 * nb) {
        int node = (t < nb) ? users[t] : (NU + items[t - nb]);
        atomicOr(&bS[node >> 5], 1u << (node & 31));
    }
}

__global__ __launch_bounds__(256) void k_markR(const int* __restrict__ row,
                                               const int* __restrict__ col,
                                               const unsigned* __restrict__ bS,
                                               unsigned* __restrict__ bR, int E) {
    int e = blockIdx.x * 256 + threadIdx.x;
    if (e < E) {
        int c = col[e];
        if ((bS[c >> 5] >> (c & 31)) & 1u) {
            int r = row[e];
            atomicOr(&bR[r >> 5], 1u << (r & 31));
        }
    }
}

// ---------------------------------------------------------------------------
// h = X @ W (64x64) + b.  16 rows/block, 256 threads (4 rows/thread).
// X == nullptr means "concat(user_table, item_table)".
// ---------------------------------------------------------------------------
__global__ __launch_bounds__(256) void k_gemm64(const float* __restrict__ X,
                                                const float* __restrict__ ut,
                                                const float* __restrict__ itb,
                                                const float* __restrict__ W,
                                                const float* __restrict__ bias,
                                                float* __restrict__ Y, int nRows) {
    __shared__ float Ws[4096];
    __shared__ float xsh[16][64];
    int tid = threadIdx.x, j = tid & 63, rq = tid >> 6;
    for (int i = tid; i < 4096; i += 256) Ws[i] = W[i];
    int r0 = blockIdx.x * 16;
    for (int i = tid; i < 1024; i += 256) {
        int rr = i >> 6, kk = i & 63;
        int r = r0 + rr;
        float v = 0.f;
        if (r < nRows) {
            v = X ? X[(size_t)r * 64 + kk]
                  : (r < NU ? ut[(size_t)r * 64 + kk]
                            : itb[(size_t)(r - NU) * 64 + kk]);
        }
        xsh[rr][kk] = v;
    }
    __syncthreads();
    float acc[4];
#pragma unroll
    for (int i = 0; i < 4; ++i) acc[i] = bias[j];
    for (int k = 0; k < 64; ++k) {
        float w = Ws[k * 64 + j];
#pragma unroll
        for (int i = 0; i < 4; ++i) acc[i] = fmaf(xsh[rq + 4 * i][k], w, acc[i]);
    }
#pragma unroll
    for (int i = 0; i < 4; ++i) {
        int r = r0 + rq + 4 * i;
        if (r < nRows) Y[(size_t)r * 64 + j] = acc[i];
    }
}

// ---------------------------------------------------------------------------
// Edge scatter: Xo[col] += nrm * H[row], filtered by bitmap on col.
// 16 threads per edge, float4 each.
// ---------------------------------------------------------------------------
__global__ __launch_bounds__(256) void k_scatter(const int* __restrict__ row,
                                                 const int* __restrict__ col,
                                                 const float* __restrict__ nrm,
                                                 const float* __restrict__ H,
                                                 const unsigned* __restrict__ filt,
                                                 float* __restrict__ Xo, int E) {
    long long t = (long long)blockIdx.x * 256 + threadIdx.x;
    int e = (int)(t >> 4);
    if (e >= E) return;
    int c = col[e];
    if (!((filt[c >> 5] >> (c & 31)) & 1u)) return;
    int q = (int)(t & 15) * 4;
    int r = row[e];
    float nv = nrm[e];
    const float4 h = *reinterpret_cast<const float4*>(H + (size_t)r * 64 + q);
    float* xp = Xo + (size_t)c * 64 + q;
    atomicAdd(xp + 0, nv * h.x);
    atomicAdd(xp + 1, nv * h.y);
    atomicAdd(xp + 2, nv * h.z);
    atomicAdd(xp + 3, nv * h.w);
}

// ---------------------------------------------------------------------------
// Gather sampled rows + corr projection: Cb[b] = X2[node(b)] @ corrW + corrB
// ---------------------------------------------------------------------------
__global__ __launch_bounds__(256) void k_corr(const float* __restrict__ X2,
                                              const int* __restrict__ users,
                                              const int* __restrict__ items,
                                              const float* __restrict__ W,
                                              const float* __restrict__ bias,
                                              float* __restrict__ Cb, int nb) {
    __shared__ float Ws[4096];
    __shared__ float xsh[16][64];
    int tid = threadIdx.x, j = tid & 63, rq = tid >> 6;
    for (int i = tid; i < 4096; i += 256) Ws[i] = W[i];
    int r0 = blockIdx.x * 16;
    for (int i = tid; i < 1024; i += 256) {
        int b = r0 + (i >> 6), kk = i & 63;
        int node = (b < nb) ? users[b] : (NU + items[b - nb]);
        xsh[i >> 6][kk] = X2[(size_t)node * 64 + kk];
    }
    __syncthreads();
    float acc[4];
#pragma unroll
    for (int i = 0; i < 4; ++i) acc[i] = bias[j];
    for (int k = 0; k < 64; ++k) {
        float w = Ws[k * 64 + j];
#pragma unroll
        for (int i = 0; i < 4; ++i) acc[i] = fmaf(xsh[rq + 4 * i][k], w, acc[i]);
    }
#pragma unroll
    for (int i = 0; i < 4; ++i) Cb[(size_t)(r0 + rq + 4 * i) * 64 + j] = acc[i];
}

// ---------------------------------------------------------------------------
// k_fuse: W_va[l] = Wv[l] @ Wo[l];  b_va[l] = bv[l] @ Wo[l] + bo[l]
// Wv = qkv_W[l][:, 128:192]. One block per layer.
// ---------------------------------------------------------------------------
__global__ __launch_bounds__(256) void k_fuse(const float* __restrict__ qkvW,
                                              const float* __restrict__ qkvB,
                                              const float* __restrict__ outW,
                                              const float* __restrict__ outB,
                                              float* __restrict__ Wva,
                                              float* __restrict__ bva) {
    int l = blockIdx.x;
    __shared__ float wo[4096];
    int tid = threadIdx.x, j = tid & 63, kq = tid >> 6;
    for (int i = tid; i < 4096; i += 256) wo[i] = outW[l * 4096 + i];
    __syncthreads();
    for (int kk = 0; kk < 16; ++kk) {
        int k = kq * 16 + kk;
        float acc = 0.f;
        for (int m = 0; m < 64; ++m)
            acc = fmaf(qkvW[(size_t)l * 64 * 192 + k * 192 + 128 + m],
                       wo[m * 64 + j], acc);
        Wva[l * 4096 + k * 64 + j] = acc;
    }
    if (tid < 64) {
        float acc = outB[l * 64 + j];
        for (int m = 0; m < 64; ++m)
            acc = fmaf(qkvB[l * 192 + 128 + m], wo[m * 64 + j], acc);
        bva[l * 64 + j] = acc;
    }
}

// ---------------------------------------------------------------------------
// k_attn: x = LN1(x + x @ W_va + b_va).  16 rows/block.
// ---------------------------------------------------------------------------
__global__ __launch_bounds__(256) void k_attn(float* __restrict__ Cb,
                                              const float* __restrict__ Wva,
                                              const float* __restrict__ bva,
                                              const float* __restrict__ g,
                                              const float* __restrict__ bt,
                                              int layer) {
    __shared__ float Ws[4096];
    __shared__ float xs[16][64];
    int tid = threadIdx.x, j = tid & 63, rq = tid >> 6;
    const float* wv = Wva + layer * 4096;
    for (int i = tid; i < 4096; i += 256) Ws[i] = wv[i];
    int row0 = blockIdx.x * 16;
    for (int i = tid; i < 1024; i += 256)
        xs[i >> 6][i & 63] = Cb[(size_t)(row0 + (i >> 6)) * 64 + (i & 63)];
    __syncthreads();
    float bv = bva[layer * 64 + j];
    float gg = g[layer * 64 + j], bb = bt[layer * 64 + j];
    float acc[4];
#pragma unroll
    for (int i = 0; i < 4; ++i) acc[i] = bv;
    for (int k = 0; k < 64; ++k) {
        float w = Ws[k * 64 + j];
#pragma unroll
        for (int i = 0; i < 4; ++i) acc[i] = fmaf(xs[rq * 4 + i][k], w, acc[i]);
    }
#pragma unroll
    for (int i = 0; i < 4; ++i) {
        int r = rq * 4 + i;
        float xv = xs[r][j] + acc[i];
        float s = xv;
#pragma unroll
        for (int o = 32; o >= 1; o >>= 1) s += __shfl_xor(s, o, 64);
        float m = s * (1.0f / 64.0f);
        float d = xv - m;
        float s2 = d * d;
#pragma unroll
        for (int o = 32; o >= 1; o >>= 1) s2 += __shfl_xor(s2, o, 64);
        float xn = d * rsqrtf(s2 * (1.0f / 64.0f) + LNEPS) * gg + bb;
        Cb[(size_t)(row0 + r) * 64 + j] = xn;
    }
}

// ---------------------------------------------------------------------------
// k_ffn1: partial FFN.  Block (rt, hc): rows rt*32..+31, hidden hc*128..+127.
// ypart[hc][row][j] = relu(x@W1c + b1c) @ W2c  (partial over this hc chunk)
// 256 threads: wave = row-group of 8; lane = hidden (t-phase) / out-dim (y).
// ---------------------------------------------------------------------------
__global__ __launch_bounds__(256) void k_ffn1(const float* __restrict__ Cb,
                                              const float* __restrict__ ff1W,
                                              const float* __restrict__ ff1B,
                                              const float* __restrict__ ff2W,
                                              float* __restrict__ ypart,
                                              int layer, int nrows) {
    __shared__ float xs[32][64];
    __shared__ float ts[32][128];
    const float* w1 = ff1W + (size_t)layer * 64 * 2048;
    const float* w2 = ff2W + (size_t)layer * 2048 * 64;
    const float* b1 = ff1B + layer * 2048;
    int tid = threadIdx.x;
    int rt = blockIdx.x;       // 0..nrows/32-1
    int hc = blockIdx.y;       // 0..15
    int row0 = rt * 32;
    for (int i = tid; i < 32 * 64; i += 256)
        xs[i >> 6][i & 63] = Cb[(size_t)(row0 + (i >> 6)) * 64 + (i & 63)];
    __syncthreads();
    int hh = tid & 63;
    int rg = tid >> 6;           // wave id = row-group of 8
    int h0 = hc * 128 + hh;
    float ta[8], tb[8];
    float bba = b1[h0], bbb = b1[h0 + 64];
#pragma unroll
    for (int i = 0; i < 8; ++i) { ta[i] = bba; tb[i] = bbb; }
    for (int k = 0; k < 64; k += 4) {
        float4 xv[8];
#pragma unroll
        for (int i = 0; i < 8; ++i)
            xv[i] = *reinterpret_cast<const float4*>(&xs[rg * 8 + i][k]);
#pragma unroll
        for (int kk = 0; kk < 4; ++kk) {
            float w1a = w1[(size_t)(k + kk) * 2048 + h0];
            float w1b = w1[(size_t)(k + kk) * 2048 + h0 + 64];
#pragma unroll
            for (int i = 0; i < 8; ++i) {
                float xvk = (kk == 0) ? xv[i].x : (kk == 1) ? xv[i].y
                          : (kk == 2) ? xv[i].z : xv[i].w;
                ta[i] = fmaf(xvk, w1a, ta[i]);
                tb[i] = fmaf(xvk, w1b, tb[i]);
            }
        }
    }
#pragma unroll
    for (int i = 0; i < 8; ++i) {
        ts[rg * 8 + i][hh]      = fmaxf(ta[i], 0.f);
        ts[rg * 8 + i][hh + 64] = fmaxf(tb[i], 0.f);
    }
    __syncthreads();
    int j = hh;
    float ya[8];
#pragma unroll
    for (int i = 0; i < 8; ++i) ya[i] = 0.f;
    for (int m = 0; m < 128; ++m) {
        float w2v = w2[(size_t)(hc * 128 + m) * 64 + j];
#pragma unroll
        for (int i = 0; i < 8; ++i) ya[i] = fmaf(ts[rg * 8 + i][m], w2v, ya[i]);
    }
#pragma unroll
    for (int i = 0; i < 8; ++i)
        ypart[((size_t)hc * nrows + row0 + rg * 8 + i) * 64 + j] = ya[i];
}

// ---------------------------------------------------------------------------
// k_ffn2: y = sum_p ypart[p]; x = LN2(x + y + b2).  16 rows/block.
// ---------------------------------------------------------------------------
__global__ __launch_bounds__(256) void k_ffn2(float* __restrict__ Cb,
                                              const float* __restrict__ ypart,
                                              const float* __restrict__ ff2B,
                                              const float* __restrict__ g,
                                              const float* __restrict__ bt,
                                              int layer, int nrows) {
    int tid = threadIdx.x;
    int j = tid & 63, rq = tid >> 6;
    int row0 = blockIdx.x * 16;
    float b2 = ff2B[layer * 64 + j];
    float gg = g[layer * 64 + j], bb = bt[layer * 64 + j];
#pragma unroll
    for (int i = 0; i < 4; ++i) {
        int r = row0 + rq * 4 + i;
        float y = 0.f;
#pragma unroll
        for (int p = 0; p < 16; ++p)
            y += ypart[((size_t)p * nrows + r) * 64 + j];
        float xv = Cb[(size_t)r * 64 + j] + y + b2;
        float s = xv;
#pragma unroll
        for (int o = 32; o >= 1; o >>= 1) s += __shfl_xor(s, o, 64);
        float m = s * (1.0f / 64.0f);
        float d = xv - m;
        float s2 = d * d;
#pragma unroll
        for (int o = 32; o >= 1; o >>= 1) s2 += __shfl_xor(s2, o, 64);
        float xn = d * rsqrtf(s2 * (1.0f / 64.0f) + LNEPS) * gg + bb;
        Cb[(size_t)r * 64 + j] = xn;
    }
}

// out[b] = dot(user_row b, item_row nb+b); quarter-wave per b.
__global__ __launch_bounds__(256) void k_dot(const float* __restrict__ Cb,
                                             float* __restrict__ out, int nb) {
    int t = blockIdx.x * 256 + threadIdx.x;
    int b = t >> 4;
    if (b >= nb) return;
    int q = (t & 15) * 4;
    const float4 u = *reinterpret_cast<const float4*>(Cb + (size_t)b * 64 + q);
    const float4 v = *reinterpret_cast<const float4*>(Cb + (size_t)(nb + b) * 64 + q);
    float s = u.x * v.x + u.y * v.y + u.z * v.z + u.w * v.w;
#pragma unroll
    for (int o = 8; o >= 1; o >>= 1) s += __shfl_xor(s, o, 16);
    if ((t & 15) == 0) out[b] = s;
}

extern "C" void kernel_launch(void* const* d_in, const int* in_sizes, int n_in,
                              void* d_out, int out_size, void* d_ws, size_t ws_size,
                              hipStream_t stream) {
    const int* users = (const int*)d_in[0];
    const int* items = (const int*)d_in[1];
    const int* ei    = (const int*)d_in[2];
    const float* ut  = (const float*)d_in[3];
    const float* itb = (const float*)d_in[4];
    const float* glW = (const float*)d_in[5];
    const float* glB = (const float*)d_in[6];
    const float* corrW = (const float*)d_in[7];
    const float* corrB = (const float*)d_in[8];
    const float* qkvW = (const float*)d_in[9];
    const float* qkvB = (const float*)d_in[10];
    const float* outW = (const float*)d_in[11];
    const float* outB = (const float*)d_in[12];
    const float* ff1W = (const float*)d_in[13];
    const float* ff1B = (const float*)d_in[14];
    const float* ff2W = (const float*)d_in[15];
    const float* ff2B = (const float*)d_in[16];
    const float* ln1g = (const float*)d_in[17];
    const float* ln1b = (const float*)d_in[18];
    const float* ln2g = (const float*)d_in[19];
    const float* ln2b = (const float*)d_in[20];

    const int E  = in_sizes[2] / 2;      // 1,750,000
    const int nb = in_sizes[0];          // 4096
    const int nrows = 2 * nb;            // 8192
    const int* rowp = ei;
    const int* colp = ei + E;

    // workspace carve-up
    char* w = (char*)d_ws;
    size_t off = 0;
    auto alloc = [&](size_t bytes) {
        char* p = w + off;
        off += (bytes + 255) & ~(size_t)255;
        return p;
    };
    float* deg = (float*)alloc((size_t)NN * 4);
    float* nrm = (float*)alloc((size_t)E * 4);
    unsigned* bS = (unsigned*)alloc(((NN + 31) / 32) * 4);
    unsigned* bR = (unsigned*)alloc(((NN + 31) / 32) * 4);
    float* bufA = (float*)alloc((size_t)NN * 64 * 4);   // 38.4 MB
    float* bufB = (float*)alloc((size_t)NN * 64 * 4);
    float* cb   = (float*)alloc((size_t)nrows * 64 * 4);
    float* Wva  = (float*)alloc(2 * 4096 * 4);
    float* bva  = (float*)alloc(2 * 64 * 4);
    float* outp = (float*)d_out;
    // ypart (16 x 8192 x 64 fp32 = 33.5 MB) overlays bufA, which is dead
    // after the second k_scatter.
    float* ypart = bufA;

    hipMemsetAsync(deg, 0, (size_t)NN * 4, stream);
    hipMemsetAsync(bS, 0, ((NN + 31) / 32) * 4, stream);
    hipMemsetAsync(bR, 0, ((NN + 31) / 32) * 4, stream);

    int eb = (E + 255) / 256;
    k_deg<<<eb, 256, 0, stream>>>(rowp, deg, E);
    k_norm<<<eb, 256, 0, stream>>>(rowp, colp, deg, nrm, E);
    k_markS<<<(2 * nb + 255) / 256, 256, 0, stream>>>(users, items, bS, nb);
    k_markR<<<eb, 256, 0, stream>>>(rowp, colp, bS, bR, E);
    k_fuse<<<2, 256, 0, stream>>>(qkvW, qkvB, outW, outB, Wva, bva);

    int gb = (NN + 15) / 16;
    int sb = (int)(((size_t)E * 16 + 255) / 256);

    // GCN layer 0: h = concat(tables)@W0+b0; x1[col in R] += nrm*h[row]
    k_gemm64<<<gb, 256, 0, stream>>>(nullptr, ut, itb, glW, glB, bufA, NN);
    hipMemsetAsync(bufB, 0, (size_t)NN * 64 * 4, stream);
    k_scatter<<<sb, 256, 0, stream>>>(rowp, colp, nrm, bufA, bR, bufB, E);

    // GCN layer 1: h2 = x1@W1+b1; x2[col in S] += nrm*h2[row]
    k_gemm64<<<gb, 256, 0, stream>>>(bufB, ut, itb, glW + 64 * 64, glB + 64, bufA, NN);
    hipMemsetAsync(bufB, 0, (size_t)NN * 64 * 4, stream);
    k_scatter<<<sb, 256, 0, stream>>>(rowp, colp, nrm, bufA, bS, bufB, E);

    // corr projection on the sampled rows
    k_corr<<<(nrows + 15) / 16, 256, 0, stream>>>(bufB, users, items, corrW, corrB, cb, nb);

    // transformer: per layer  attn+LN1  ->  partial FFN  ->  reduce+LN2
    dim3 fgrid(nrows / 32, 16);
    for (int l = 0; l < 2; ++l) {
        k_attn<<<nrows / 16, 256, 0, stream>>>(cb, Wva, bva, ln1g, ln1b, l);
        k_ffn1<<<fgrid, 256, 0, stream>>>(cb, ff1W, ff1B, ff2W, ypart, l, nrows);
        k_ffn2<<<nrows / 16, 256, 0, stream>>>(cb, ypart, ff2B, ln2g, ln2b, l, nrows);
    }
    k_dot<<<(nb * 16 + 255) / 256, 256, 0, stream>>>(cb, outp, nb);
}

// Round 4
// 894.985 us; speedup vs baseline: 3.7946x; 3.5476x over previous
//
#include <hip/hip_runtime.h>
#include <math.h>

// Problem constants (fixed by the reference's setup_inputs)
#define NU 100000
#define NI 50000
#define NN 150000          // NU + NI
#define NNP 150528         // NN padded to 147*1024 for the scan
#define SCNB 147           // scan blocks (1024 elems each)
#define LNEPS 1e-5f

// ---------------------------------------------------------------------------
// Bitmaps: S = sampled nodes; R = rows of edges whose col is in S.
// ---------------------------------------------------------------------------
__global__ __launch_bounds__(256) void k_markS(const int* __restrict__ users,
                                               const int* __restrict__ items,
                                               unsigned* __restrict__ bS, int nb) {
    int t = blockIdx.x * 256 + threadIdx.x;
    if (t < 2 * nb) {
        int node = (t < nb) ? users[t] : (NU + items[t - nb]);
        atomicOr(&bS[node >> 5], 1u << (node & 31));
    }
}

// deg (out-degree over row, int) + markR in one edge pass.
__global__ __launch_bounds__(256) void k_pre1(const int* __restrict__ row,
                                              const int* __restrict__ col,
                                              const unsigned* __restrict__ bS,
                                              int* __restrict__ deg,
                                              unsigned* __restrict__ bR, int E) {
    int e = blockIdx.x * 256 + threadIdx.x;
    if (e >= E) return;
    int r = row[e];
    atomicAdd(&deg[r], 1);
    int c = col[e];
    if ((bS[c >> 5] >> (c & 31)) & 1u) atomicOr(&bR[r >> 5], 1u << (r & 31));
}

__global__ __launch_bounds__(256) void k_dis(const int* __restrict__ deg,
                                             float* __restrict__ dis) {
    int i = blockIdx.x * 256 + threadIdx.x;
    if (i < NN) dis[i] = rsqrtf((float)deg[i]);
}

// count edges per col, only for cols in R
__global__ __launch_bounds__(256) void k_cnt(const int* __restrict__ col,
                                             const unsigned* __restrict__ bR,
                                             int* __restrict__ cnt, int E) {
    int e = blockIdx.x * 256 + threadIdx.x;
    if (e >= E) return;
    int c = col[e];
    if ((bR[c >> 5] >> (c & 31)) & 1u) atomicAdd(&cnt[c], 1);
}

// ---------------------------------------------------------------------------
// Exclusive scan of cnt[NNP] -> start[NNP+1] (3-kernel textbook scan)
// ---------------------------------------------------------------------------
__global__ __launch_bounds__(256) void k_scan1(const int* __restrict__ cnt,
                                               int* __restrict__ bsum) {
    __shared__ int sh[256];
    int b = blockIdx.x, t = threadIdx.x;
    int4 v = ((const int4*)cnt)[b * 256 + t];
    sh[t] = v.x + v.y + v.z + v.w;
    __syncthreads();
    for (int off = 128; off >= 1; off >>= 1) {
        if (t < off) sh[t] += sh[t + off];
        __syncthreads();
    }
    if (t == 0) bsum[b] = sh[0];
}

__global__ void k_scan2(int* __restrict__ bsum, int nblk) {
    if (threadIdx.x == 0 && blockIdx.x == 0) {
        int acc = 0;
        for (int i = 0; i < nblk; ++i) { int v = bsum[i]; bsum[i] = acc; acc += v; }
    }
}

__global__ __launch_bounds__(256) void k_scan3(const int* __restrict__ cnt,
                                               const int* __restrict__ bsum,
                                               int* __restrict__ start) {
    __shared__ int sh[257];
    int b = blockIdx.x, t = threadIdx.x;
    int4 v = ((const int4*)cnt)[b * 256 + t];
    int s = v.x + v.y + v.z + v.w;
    sh[t + 1] = s;
    if (t == 0) sh[0] = 0;
    __syncthreads();
    for (int off = 1; off < 256; off <<= 1) {
        int add = sh[t + 1] + ((t + 1 > off) ? sh[t + 1 - off] : 0);
        __syncthreads();
        sh[t + 1] = add;
        __syncthreads();
    }
    int base = bsum[b] + sh[t];   // exclusive prefix for this thread's 4 elems
    int i0 = b * 1024 + t * 4;
    start[i0 + 0] = base;  base += v.x;
    start[i0 + 1] = base;  base += v.y;
    start[i0 + 2] = base;  base += v.z;
    start[i0 + 3] = base;
    if (b == SCNB - 1 && t == 255) start[NNP] = base + v.w;
}

// place packed {row, nrm} into CSR slots (order within a col is arbitrary)
__global__ __launch_bounds__(256) void k_place(const int* __restrict__ row,
                                               const int* __restrict__ col,
                                               const unsigned* __restrict__ bR,
                                               const float* __restrict__ dis,
                                               const int* __restrict__ start,
                                               int* __restrict__ cur,
                                               int2* __restrict__ el, int E) {
    int e = blockIdx.x * 256 + threadIdx.x;
    if (e >= E) return;
    int c = col[e];
    if (!((bR[c >> 5] >> (c & 31)) & 1u)) return;
    int r = row[e];
    float nv = dis[r] * dis[c];
    int pos = atomicAdd(&cur[c], 1);
    el[start[c] + pos] = make_int2(r, __float_as_int(nv));
}

// ---------------------------------------------------------------------------
// Gather aggregation: one wave per col.  X[c][j] = sum_e nrm_e * H[row_e][j].
// filt==nullptr: process any col with a non-empty list (== cols in R).
// ---------------------------------------------------------------------------
__global__ __launch_bounds__(256) void k_gather(const int2* __restrict__ el,
                                                const int* __restrict__ start,
                                                const float* __restrict__ H,
                                                float* __restrict__ X,
                                                const unsigned* __restrict__ filt) {
    int wid = (blockIdx.x * 256 + threadIdx.x) >> 6;
    int j = threadIdx.x & 63;
    if (wid >= NN) return;
    if (filt && !((filt[wid >> 5] >> (wid & 31)) & 1u)) return;
    int s = start[wid], e = start[wid + 1];
    if (s == e) return;
    float acc0 = 0.f, acc1 = 0.f;
    int i = s;
    for (; i + 1 < e; i += 2) {
        int2 e0 = el[i], e1 = el[i + 1];
        acc0 = fmaf(__int_as_float(e0.y), H[(size_t)e0.x * 64 + j], acc0);
        acc1 = fmaf(__int_as_float(e1.y), H[(size_t)e1.x * 64 + j], acc1);
    }
    if (i < e) {
        int2 e0 = el[i];
        acc0 = fmaf(__int_as_float(e0.y), H[(size_t)e0.x * 64 + j], acc0);
    }
    X[(size_t)wid * 64 + j] = acc0 + acc1;
}

// ---------------------------------------------------------------------------
// h = X @ W (64x64) + b.  16 rows/block, 256 threads (4 rows/thread).
// X == nullptr means "concat(user_table, item_table)".
// ---------------------------------------------------------------------------
__global__ __launch_bounds__(256) void k_gemm64(const float* __restrict__ X,
                                                const float* __restrict__ ut,
                                                const float* __restrict__ itb,
                                                const float* __restrict__ W,
                                                const float* __restrict__ bias,
                                                float* __restrict__ Y, int nRows) {
    __shared__ float Ws[4096];
    __shared__ float xsh[16][64];
    int tid = threadIdx.x, j = tid & 63, rq = tid >> 6;
    for (int i = tid; i < 4096; i += 256) Ws[i] = W[i];
    int r0 = blockIdx.x * 16;
    for (int i = tid; i < 1024; i += 256) {
        int rr = i >> 6, kk = i & 63;
        int r = r0 + rr;
        float v = 0.f;
        if (r < nRows) {
            v = X ? X[(size_t)r * 64 + kk]
                  : (r < NU ? ut[(size_t)r * 64 + kk]
                            : itb[(size_t)(r - NU) * 64 + kk]);
        }
        xsh[rr][kk] = v;
    }
    __syncthreads();
    float acc[4];
#pragma unroll
    for (int i = 0; i < 4; ++i) acc[i] = bias[j];
    for (int k = 0; k < 64; ++k) {
        float w = Ws[k * 64 + j];
#pragma unroll
        for (int i = 0; i < 4; ++i) acc[i] = fmaf(xsh[rq + 4 * i][k], w, acc[i]);
    }
#pragma unroll
    for (int i = 0; i < 4; ++i) {
        int r = r0 + rq + 4 * i;
        if (r < nRows) Y[(size_t)r * 64 + j] = acc[i];
    }
}

// ---------------------------------------------------------------------------
// Gather sampled rows + corr projection: Cb[b] = X2[node(b)] @ corrW + corrB
// ---------------------------------------------------------------------------
__global__ __launch_bounds__(256) void k_corr(const float* __restrict__ X2,
                                              const int* __restrict__ users,
                                              const int* __restrict__ items,
                                              const float* __restrict__ W,
                                              const float* __restrict__ bias,
                                              float* __restrict__ Cb, int nb) {
    __shared__ float Ws[4096];
    __shared__ float xsh[16][64];
    int tid = threadIdx.x, j = tid & 63, rq = tid >> 6;
    for (int i = tid; i < 4096; i += 256) Ws[i] = W[i];
    int r0 = blockIdx.x * 16;
    for (int i = tid; i < 1024; i += 256) {
        int b = r0 + (i >> 6), kk = i & 63;
        int node = (b < nb) ? users[b] : (NU + items[b - nb]);
        xsh[i >> 6][kk] = X2[(size_t)node * 64 + kk];
    }
    __syncthreads();
    float acc[4];
#pragma unroll
    for (int i = 0; i < 4; ++i) acc[i] = bias[j];
    for (int k = 0; k < 64; ++k) {
        float w = Ws[k * 64 + j];
#pragma unroll
        for (int i = 0; i < 4; ++i) acc[i] = fmaf(xsh[rq + 4 * i][k], w, acc[i]);
    }
#pragma unroll
    for (int i = 0; i < 4; ++i) Cb[(size_t)(r0 + rq + 4 * i) * 64 + j] = acc[i];
}

// ---------------------------------------------------------------------------
// k_fuse: W_va[l] = Wv[l] @ Wo[l];  b_va[l] = bv[l] @ Wo[l] + bo[l]
// ---------------------------------------------------------------------------
__global__ __launch_bounds__(256) void k_fuse(const float* __restrict__ qkvW,
                                              const float* __restrict__ qkvB,
                                              const float* __restrict__ outW,
                                              const float* __restrict__ outB,
                                              float* __restrict__ Wva,
                                              float* __restrict__ bva) {
    int l = blockIdx.x;
    __shared__ float wo[4096];
    int tid = threadIdx.x, j = tid & 63, kq = tid >> 6;
    for (int i = tid; i < 4096; i += 256) wo[i] = outW[l * 4096 + i];
    __syncthreads();
    for (int kk = 0; kk < 16; ++kk) {
        int k = kq * 16 + kk;
        float acc = 0.f;
        for (int m = 0; m < 64; ++m)
            acc = fmaf(qkvW[(size_t)l * 64 * 192 + k * 192 + 128 + m],
                       wo[m * 64 + j], acc);
        Wva[l * 4096 + k * 64 + j] = acc;
    }
    if (tid < 64) {
        float acc = outB[l * 64 + j];
        for (int m = 0; m < 64; ++m)
            acc = fmaf(qkvB[l * 192 + 128 + m], wo[m * 64 + j], acc);
        bva[l * 64 + j] = acc;
    }
}

// ---------------------------------------------------------------------------
// k_attn: x = LN1(x + x @ W_va + b_va).  16 rows/block.
// ---------------------------------------------------------------------------
__global__ __launch_bounds__(256) void k_attn(float* __restrict__ Cb,
                                              const float* __restrict__ Wva,
                                              const float* __restrict__ bva,
                                              const float* __restrict__ g,
                                              const float* __restrict__ bt,
                                              int layer) {
    __shared__ float Ws[4096];
    __shared__ float xs[16][64];
    int tid = threadIdx.x, j = tid & 63, rq = tid >> 6;
    const float* wv = Wva + layer * 4096;
    for (int i = tid; i < 4096; i += 256) Ws[i] = wv[i];
    int row0 = blockIdx.x * 16;
    for (int i = tid; i < 1024; i += 256)
        xs[i >> 6][i & 63] = Cb[(size_t)(row0 + (i >> 6)) * 64 + (i & 63)];
    __syncthreads();
    float bv = bva[layer * 64 + j];
    float gg = g[layer * 64 + j], bb = bt[layer * 64 + j];
    float acc[4];
#pragma unroll
    for (int i = 0; i < 4; ++i) acc[i] = bv;
    for (int k = 0; k < 64; ++k) {
        float w = Ws[k * 64 + j];
#pragma unroll
        for (int i = 0; i < 4; ++i) acc[i] = fmaf(xs[rq * 4 + i][k], w, acc[i]);
    }
#pragma unroll
    for (int i = 0; i < 4; ++i) {
        int r = rq * 4 + i;
        float xv = xs[r][j] + acc[i];
        float s = xv;
#pragma unroll
        for (int o = 32; o >= 1; o >>= 1) s += __shfl_xor(s, o, 64);
        float m = s * (1.0f / 64.0f);
        float d = xv - m;
        float s2 = d * d;
#pragma unroll
        for (int o = 32; o >= 1; o >>= 1) s2 += __shfl_xor(s2, o, 64);
        float xn = d * rsqrtf(s2 * (1.0f / 64.0f) + LNEPS) * gg + bb;
        Cb[(size_t)(row0 + r) * 64 + j] = xn;
    }
}

// ---------------------------------------------------------------------------
// k_ffn1: partial FFN.  Block (rt, hc): rows rt*32..+31, hidden hc*128..+127.
// ---------------------------------------------------------------------------
__global__ __launch_bounds__(256) void k_ffn1(const float* __restrict__ Cb,
                                              const float* __restrict__ ff1W,
                                              const float* __restrict__ ff1B,
                                              const float* __restrict__ ff2W,
                                              float* __restrict__ ypart,
                                              int layer, int nrows) {
    __shared__ float xs[32][64];
    __shared__ float ts[32][128];
    const float* w1 = ff1W + (size_t)layer * 64 * 2048;
    const float* w2 = ff2W + (size_t)layer * 2048 * 64;
    const float* b1 = ff1B + layer * 2048;
    int tid = threadIdx.x;
    int rt = blockIdx.x;
    int hc = blockIdx.y;
    int row0 = rt * 32;
    for (int i = tid; i < 32 * 64; i += 256)
        xs[i >> 6][i & 63] = Cb[(size_t)(row0 + (i >> 6)) * 64 + (i & 63)];
    __syncthreads();
    int hh = tid & 63;
    int rg = tid >> 6;
    int h0 = hc * 128 + hh;
    float ta[8], tb[8];
    float bba = b1[h0], bbb = b1[h0 + 64];
#pragma unroll
    for (int i = 0; i < 8; ++i) { ta[i] = bba; tb[i] = bbb; }
    for (int k = 0; k < 64; k += 4) {
        float4 xv[8];
#pragma unroll
        for (int i = 0; i < 8; ++i)
            xv[i] = *reinterpret_cast<const float4*>(&xs[rg * 8 + i][k]);
#pragma unroll
        for (int kk = 0; kk < 4; ++kk) {
            float w1a = w1[(size_t)(k + kk) * 2048 + h0];
            float w1b = w1[(size_t)(k + kk) * 2048 + h0 + 64];
#pragma unroll
            for (int i = 0; i < 8; ++i) {
                float xvk = (kk == 0) ? xv[i].x : (kk == 1) ? xv[i].y
                          : (kk == 2) ? xv[i].z : xv[i].w;
                ta[i] = fmaf(xvk, w1a, ta[i]);
                tb[i] = fmaf(xvk, w1b, tb[i]);
            }
        }
    }
#pragma unroll
    for (int i = 0; i < 8; ++i) {
        ts[rg * 8 + i][hh]      = fmaxf(ta[i], 0.f);
        ts[rg * 8 + i][hh + 64] = fmaxf(tb[i], 0.f);
    }
    __syncthreads();
    int j = hh;
    float ya[8];
#pragma unroll
    for (int i = 0; i < 8; ++i) ya[i] = 0.f;
    for (int m = 0; m < 128; ++m) {
        float w2v = w2[(size_t)(hc * 128 + m) * 64 + j];
#pragma unroll
        for (int i = 0; i < 8; ++i) ya[i] = fmaf(ts[rg * 8 + i][m], w2v, ya[i]);
    }
#pragma unroll
    for (int i = 0; i < 8; ++i)
        ypart[((size_t)hc * nrows + row0 + rg * 8 + i) * 64 + j] = ya[i];
}

// ---------------------------------------------------------------------------
// k_ffn2: y = sum_p ypart[p]; x = LN2(x + y + b2).  16 rows/block.
// ---------------------------------------------------------------------------
__global__ __launch_bounds__(256) void k_ffn2(float* __restrict__ Cb,
                                              const float* __restrict__ ypart,
                                              const float* __restrict__ ff2B,
                                              const float* __restrict__ g,
                                              const float* __restrict__ bt,
                                              int layer, int nrows) {
    int tid = threadIdx.x;
    int j = tid & 63, rq = tid >> 6;
    int row0 = blockIdx.x * 16;
    float b2 = ff2B[layer * 64 + j];
    float gg = g[layer * 64 + j], bb = bt[layer * 64 + j];
#pragma unroll
    for (int i = 0; i < 4; ++i) {
        int r = row0 + rq * 4 + i;
        float y = 0.f;
#pragma unroll
        for (int p = 0; p < 16; ++p)
            y += ypart[((size_t)p * nrows + r) * 64 + j];
        float xv = Cb[(size_t)r * 64 + j] + y + b2;
        float s = xv;
#pragma unroll
        for (int o = 32; o >= 1; o >>= 1) s += __shfl_xor(s, o, 64);
        float m = s * (1.0f / 64.0f);
        float d = xv - m;
        float s2 = d * d;
#pragma unroll
        for (int o = 32; o >= 1; o >>= 1) s2 += __shfl_xor(s2, o, 64);
        float xn = d * rsqrtf(s2 * (1.0f / 64.0f) + LNEPS) * gg + bb;
        Cb[(size_t)r * 64 + j] = xn;
    }
}

// out[b] = dot(user_row b, item_row nb+b); quarter-wave per b.
__global__ __launch_bounds__(256) void k_dot(const float* __restrict__ Cb,
                                             float* __restrict__ out, int nb) {
    int t = blockIdx.x * 256 + threadIdx.x;
    int b = t >> 4;
    if (b >= nb) return;
    int q = (t & 15) * 4;
    const float4 u = *reinterpret_cast<const float4*>(Cb + (size_t)b * 64 + q);
    const float4 v = *reinterpret_cast<const float4*>(Cb + (size_t)(nb + b) * 64 + q);
    float s = u.x * v.x + u.y * v.y + u.z * v.z + u.w * v.w;
#pragma unroll
    for (int o = 8; o >= 1; o >>= 1) s += __shfl_xor(s, o, 16);
    if ((t & 15) == 0) out[b] = s;
}

extern "C" void kernel_launch(void* const* d_in, const int* in_sizes, int n_in,
                              void* d_out, int out_size, void* d_ws, size_t ws_size,
                              hipStream_t stream) {
    const int* users = (const int*)d_in[0];
    const int* items = (const int*)d_in[1];
    const int* ei    = (const int*)d_in[2];
    const float* ut  = (const float*)d_in[3];
    const float* itb = (const float*)d_in[4];
    const float* glW = (const float*)d_in[5];
    const float* glB = (const float*)d_in[6];
    const float* corrW = (const float*)d_in[7];
    const float* corrB = (const float*)d_in[8];
    const float* qkvW = (const float*)d_in[9];
    const float* qkvB = (const float*)d_in[10];
    const float* outW = (const float*)d_in[11];
    const float* outB = (const float*)d_in[12];
    const float* ff1W = (const float*)d_in[13];
    const float* ff1B = (const float*)d_in[14];
    const float* ff2W = (const float*)d_in[15];
    const float* ff2B = (const float*)d_in[16];
    const float* ln1g = (const float*)d_in[17];
    const float* ln1b = (const float*)d_in[18];
    const float* ln2g = (const float*)d_in[19];
    const float* ln2b = (const float*)d_in[20];

    const int E  = in_sizes[2] / 2;      // 1,750,000
    const int nb = in_sizes[0];          // 4096
    const int nrows = 2 * nb;            // 8192
    const int* rowp = ei;
    const int* colp = ei + E;

    // workspace carve-up (~98 MB)
    char* w = (char*)d_ws;
    size_t off = 0;
    auto alloc = [&](size_t bytes) {
        char* p = w + off;
        off += (bytes + 255) & ~(size_t)255;
        return p;
    };
    int*      deg   = (int*)alloc((size_t)NN * 4);
    float*    dis   = (float*)alloc((size_t)NN * 4);
    unsigned* bS    = (unsigned*)alloc(((NN + 31) / 32) * 4);
    unsigned* bR    = (unsigned*)alloc(((NN + 31) / 32) * 4);
    int*      cnt   = (int*)alloc((size_t)NNP * 4);
    int*      start = (int*)alloc((size_t)(NNP + 1) * 4);
    int*      cur   = (int*)alloc((size_t)NN * 4);
    int*      bsum  = (int*)alloc((size_t)SCNB * 4);
    int2*     el    = (int2*)alloc((size_t)E * 8);
    float*    bufA  = (float*)alloc((size_t)NN * 64 * 4);   // 38.4 MB
    float*    bufB  = (float*)alloc((size_t)NN * 64 * 4);
    float*    cb    = (float*)alloc((size_t)nrows * 64 * 4);
    float*    Wva   = (float*)alloc(2 * 4096 * 4);
    float*    bva   = (float*)alloc(2 * 64 * 4);
    float*    outp  = (float*)d_out;
    float*    ypart = bufA;   // 33.5 MB overlay; bufA dead after layer-2 gather

    hipMemsetAsync(deg, 0, (size_t)NN * 4, stream);
    hipMemsetAsync(bS, 0, ((NN + 31) / 32) * 4, stream);
    hipMemsetAsync(bR, 0, ((NN + 31) / 32) * 4, stream);
    hipMemsetAsync(cnt, 0, (size_t)NNP * 4, stream);
    hipMemsetAsync(cur, 0, (size_t)NN * 4, stream);

    int eb = (E + 255) / 256;
    int nnb = (NN + 255) / 256;

    // --- CSR build ---
    k_markS<<<(2 * nb + 255) / 256, 256, 0, stream>>>(users, items, bS, nb);
    k_pre1<<<eb, 256, 0, stream>>>(rowp, colp, bS, deg, bR, E);
    k_dis<<<nnb, 256, 0, stream>>>(deg, dis);
    k_cnt<<<eb, 256, 0, stream>>>(colp, bR, cnt, E);
    k_scan1<<<SCNB, 256, 0, stream>>>(cnt, bsum);
    k_scan2<<<1, 64, 0, stream>>>(bsum, SCNB);
    k_scan3<<<SCNB, 256, 0, stream>>>(cnt, bsum, start);
    k_place<<<eb, 256, 0, stream>>>(rowp, colp, bR, dis, start, cur, el, E);
    k_fuse<<<2, 256, 0, stream>>>(qkvW, qkvB, outW, outB, Wva, bva);

    int gb = (NN + 15) / 16;
    int agb = (NN + 3) / 4;    // 4 waves/block, 1 wave per col

    // GCN layer 0: h = concat(tables)@W0+b0; x1[c in R] = gather
    k_gemm64<<<gb, 256, 0, stream>>>(nullptr, ut, itb, glW, glB, bufA, NN);
    k_gather<<<agb, 256, 0, stream>>>(el, start, bufA, bufB, nullptr);

    // GCN layer 1: h2 = x1@W1+b1; x2[c in S] = gather
    k_gemm64<<<gb, 256, 0, stream>>>(bufB, ut, itb, glW + 64 * 64, glB + 64, bufA, NN);
    k_gather<<<agb, 256, 0, stream>>>(el, start, bufA, bufB, bS);

    // corr projection on the sampled rows
    k_corr<<<(nrows + 15) / 16, 256, 0, stream>>>(bufB, users, items, corrW, corrB, cb, nb);

    // transformer: per layer  attn+LN1 -> partial FFN -> reduce+LN2
    dim3 fgrid(nrows / 32, 16);
    for (int l = 0; l < 2; ++l) {
        k_attn<<<nrows / 16, 256, 0, stream>>>(cb, Wva, bva, ln1g, ln1b, l);
        k_ffn1<<<fgrid, 256, 0, stream>>>(cb, ff1W, ff1B, ff2W, ypart, l, nrows);
        k_ffn2<<<nrows / 16, 256, 0, stream>>>(cb, ypart, ff2B, ln2g, ln2b, l, nrows);
    }
    k_dot<<<(nb * 16 + 255) / 256, 256, 0, stream>>>(cb, outp, nb);
}

// Round 6
// 591.239 us; speedup vs baseline: 5.7440x; 1.5137x over previous
//
#include <hip/hip_runtime.h>
#include <math.h>

// Problem constants (fixed by the reference's setup_inputs)
#define NU 100000
#define NI 50000
#define NN 150000          // NU + NI
#define NNP 150528         // NN padded to 147*1024 for the scan
#define SCNB 147           // scan blocks (1024 elems each)
#define LNEPS 1e-5f

// ---------------------------------------------------------------------------
// Bitmaps: S = sampled nodes; R = rows of edges whose col is in S.
// ---------------------------------------------------------------------------
__global__ __launch_bounds__(256) void k_markS(const int* __restrict__ users,
                                               const int* __restrict__ items,
                                               unsigned* __restrict__ bS, int nb) {
    int t = blockIdx.x * 256 + threadIdx.x;
    if (t < 2 * nb) {
        int node = (t < nb) ? users[t] : (NU + items[t - nb]);
        atomicOr(&bS[node >> 5], 1u << (node & 31));
    }
}

// deg (out-degree over row, int) + markR in one edge pass.
__global__ __launch_bounds__(256) void k_pre1(const int* __restrict__ row,
                                              const int* __restrict__ col,
                                              const unsigned* __restrict__ bS,
                                              int* __restrict__ deg,
                                              unsigned* __restrict__ bR, int E) {
    int e = blockIdx.x * 256 + threadIdx.x;
    if (e >= E) return;
    int r = row[e];
    atomicAdd(&deg[r], 1);
    int c = col[e];
    if ((bS[c >> 5] >> (c & 31)) & 1u) atomicOr(&bR[r >> 5], 1u << (r & 31));
}

__global__ __launch_bounds__(256) void k_dis(const int* __restrict__ deg,
                                             float* __restrict__ dis) {
    int i = blockIdx.x * 256 + threadIdx.x;
    if (i < NN) dis[i] = rsqrtf((float)deg[i]);
}

// count edges per col, only for cols in R
__global__ __launch_bounds__(256) void k_cnt(const int* __restrict__ col,
                                             const unsigned* __restrict__ bR,
                                             int* __restrict__ cnt, int E) {
    int e = blockIdx.x * 256 + threadIdx.x;
    if (e >= E) return;
    int c = col[e];
    if ((bR[c >> 5] >> (c & 31)) & 1u) atomicAdd(&cnt[c], 1);
}

// ---------------------------------------------------------------------------
// Exclusive scan of cnt[NNP] -> start[NNP+1]
// ---------------------------------------------------------------------------
__global__ __launch_bounds__(256) void k_scan1(const int* __restrict__ cnt,
                                               int* __restrict__ bsum) {
    __shared__ int sh[256];
    int b = blockIdx.x, t = threadIdx.x;
    int4 v = ((const int4*)cnt)[b * 256 + t];
    sh[t] = v.x + v.y + v.z + v.w;
    __syncthreads();
    for (int off = 128; off >= 1; off >>= 1) {
        if (t < off) sh[t] += sh[t + off];
        __syncthreads();
    }
    if (t == 0) bsum[b] = sh[0];
}

// wave-parallel exclusive scan of the 147 block sums (single block)
__global__ __launch_bounds__(256) void k_scan2(int* __restrict__ bsum, int nblk) {
    __shared__ int sh[256];
    int t = threadIdx.x;
    int v = (t < nblk) ? bsum[t] : 0;
    sh[t] = v;
    __syncthreads();
    for (int off = 1; off < 256; off <<= 1) {
        int add = (t >= off) ? sh[t - off] : 0;
        __syncthreads();
        sh[t] += add;
        __syncthreads();
    }
    if (t < nblk) bsum[t] = sh[t] - v;   // exclusive
}

__global__ __launch_bounds__(256) void k_scan3(const int* __restrict__ cnt,
                                               const int* __restrict__ bsum,
                                               int* __restrict__ start) {
    __shared__ int sh[257];
    int b = blockIdx.x, t = threadIdx.x;
    int4 v = ((const int4*)cnt)[b * 256 + t];
    int s = v.x + v.y + v.z + v.w;
    sh[t + 1] = s;
    if (t == 0) sh[0] = 0;
    __syncthreads();
    for (int off = 1; off < 256; off <<= 1) {
        int add = sh[t + 1] + ((t + 1 > off) ? sh[t + 1 - off] : 0);
        __syncthreads();
        sh[t + 1] = add;
        __syncthreads();
    }
    int base = bsum[b] + sh[t];
    int i0 = b * 1024 + t * 4;
    start[i0 + 0] = base;  base += v.x;
    start[i0 + 1] = base;  base += v.y;
    start[i0 + 2] = base;  base += v.z;
    start[i0 + 3] = base;
    if (b == SCNB - 1 && t == 255) start[NNP] = base + v.w;
}

// place packed {row, nrm} into CSR slots (order within a col is arbitrary)
__global__ __launch_bounds__(256) void k_place(const int* __restrict__ row,
                                               const int* __restrict__ col,
                                               const unsigned* __restrict__ bR,
                                               const float* __restrict__ dis,
                                               const int* __restrict__ start,
                                               int* __restrict__ cur,
                                               int2* __restrict__ el, int E) {
    int e = blockIdx.x * 256 + threadIdx.x;
    if (e >= E) return;
    int c = col[e];
    if (!((bR[c >> 5] >> (c & 31)) & 1u)) return;
    int r = row[e];
    float nv = dis[r] * dis[c];
    int pos = atomicAdd(&cur[c], 1);
    el[start[c] + pos] = make_int2(r, __float_as_int(nv));
}

// ---------------------------------------------------------------------------
// gather1: g1[c] = sum nrm * x_raw[row];  sdeg[c] = sum nrm.   cols in R
// (== cols with non-empty lists).  One wave per col.
// ---------------------------------------------------------------------------
__global__ __launch_bounds__(256) void k_gather1(const int2* __restrict__ el,
                                                 const int* __restrict__ start,
                                                 const float* __restrict__ ut,
                                                 const float* __restrict__ itb,
                                                 float* __restrict__ g1,
                                                 float* __restrict__ sdeg) {
    int wid = (blockIdx.x * 256 + threadIdx.x) >> 6;
    int j = threadIdx.x & 63;
    if (wid >= NN) return;
    int s = start[wid], e = start[wid + 1];
    if (s == e) return;
    float acc0 = 0.f, acc1 = 0.f, sn = 0.f;
    int i = s;
    for (; i + 1 < e; i += 2) {
        int2 e0 = el[i], e1 = el[i + 1];
        float n0 = __int_as_float(e0.y), n1 = __int_as_float(e1.y);
        const float* s0 = (e0.x < NU) ? ut + (size_t)e0.x * 64
                                      : itb + (size_t)(e0.x - NU) * 64;
        const float* s1 = (e1.x < NU) ? ut + (size_t)e1.x * 64
                                      : itb + (size_t)(e1.x - NU) * 64;
        acc0 = fmaf(n0, s0[j], acc0);
        acc1 = fmaf(n1, s1[j], acc1);
        sn += n0 + n1;
    }
    if (i < e) {
        int2 e0 = el[i];
        float n0 = __int_as_float(e0.y);
        const float* s0 = (e0.x < NU) ? ut + (size_t)e0.x * 64
                                      : itb + (size_t)(e0.x - NU) * 64;
        acc0 = fmaf(n0, s0[j], acc0);
        sn += n0;
    }
    g1[(size_t)wid * 64 + j] = acc0 + acc1;
    if (j == 0) sdeg[wid] = sn;
}

// ---------------------------------------------------------------------------
// gather2: gg[c] = sum nrm * g1[row];  s2[c] = sum nrm * sdeg[row].  cols in S.
// ---------------------------------------------------------------------------
__global__ __launch_bounds__(256) void k_gather2(const int2* __restrict__ el,
                                                 const int* __restrict__ start,
                                                 const float* __restrict__ g1,
                                                 const float* __restrict__ sdeg,
                                                 const unsigned* __restrict__ bS,
                                                 float* __restrict__ gg,
                                                 float* __restrict__ s2) {
    int wid = (blockIdx.x * 256 + threadIdx.x) >> 6;
    int j = threadIdx.x & 63;
    if (wid >= NN) return;
    if (!((bS[wid >> 5] >> (wid & 31)) & 1u)) return;
    int s = start[wid], e = start[wid + 1];
    float acc0 = 0.f, acc1 = 0.f, sa = 0.f;
    int i = s;
    for (; i + 1 < e; i += 2) {
        int2 e0 = el[i], e1 = el[i + 1];
        float n0 = __int_as_float(e0.y), n1 = __int_as_float(e1.y);
        acc0 = fmaf(n0, g1[(size_t)e0.x * 64 + j], acc0);
        acc1 = fmaf(n1, g1[(size_t)e1.x * 64 + j], acc1);
        sa = fmaf(n0, sdeg[e0.x], sa);
        sa = fmaf(n1, sdeg[e1.x], sa);
    }
    if (i < e) {
        int2 e0 = el[i];
        float n0 = __int_as_float(e0.y);
        acc0 = fmaf(n0, g1[(size_t)e0.x * 64 + j], acc0);
        sa = fmaf(n0, sdeg[e0.x], sa);
    }
    gg[(size_t)wid * 64 + j] = acc0 + acc1;
    if (j == 0) s2[wid] = sa;
}

// ---------------------------------------------------------------------------
// k_fuse: W_va[l] = Wv[l] @ Wo[l];  b_va[l] = bv[l] @ Wo[l] + bo[l]
// ---------------------------------------------------------------------------
__global__ __launch_bounds__(256) void k_fuse(const float* __restrict__ qkvW,
                                              const float* __restrict__ qkvB,
                                              const float* __restrict__ outW,
                                              const float* __restrict__ outB,
                                              float* __restrict__ Wva,
                                              float* __restrict__ bva) {
    int l = blockIdx.x;
    __shared__ float wo[4096];
    int tid = threadIdx.x, j = tid & 63, kq = tid >> 6;
    for (int i = tid; i < 4096; i += 256) wo[i] = outW[l * 4096 + i];
    __syncthreads();
    for (int kk = 0; kk < 16; ++kk) {
        int k = kq * 16 + kk;
        float acc = 0.f;
        for (int m = 0; m < 64; ++m)
            acc = fmaf(qkvW[(size_t)l * 64 * 192 + k * 192 + 128 + m],
                       wo[m * 64 + j], acc);
        Wva[l * 4096 + k * 64 + j] = acc;
    }
    if (tid < 64) {
        float acc = outB[l * 64 + j];
        for (int m = 0; m < 64; ++m)
            acc = fmaf(qkvB[l * 192 + 128 + m], wo[m * 64 + j], acc);
        bva[l * 64 + j] = acc;
    }
}

// ---------------------------------------------------------------------------
// k_fuse2: Wff = W0@W1@corrW; bff = [b0@W1@corrW, b1@corrW, corrB]
// ---------------------------------------------------------------------------
__global__ __launch_bounds__(256) void k_fuse2(const float* __restrict__ glW,
                                               const float* __restrict__ glB,
                                               const float* __restrict__ corrW,
                                               const float* __restrict__ corrB,
                                               float* __restrict__ Wff,
                                               float* __restrict__ bff) {
    __shared__ float A[4096];   // W1
    __shared__ float B[4096];   // corrW
    __shared__ float T[4096];   // W0@W1
    __shared__ float vec[64];
    int tid = threadIdx.x, j = tid & 63, kq = tid >> 6;
    for (int i = tid; i < 4096; i += 256) { A[i] = glW[4096 + i]; B[i] = corrW[i]; }
    __syncthreads();
    for (int kk = 0; kk < 16; ++kk) {
        int k = kq * 16 + kk;
        float acc = 0.f;
        for (int m = 0; m < 64; ++m) acc = fmaf(glW[k * 64 + m], A[m * 64 + j], acc);
        T[k * 64 + j] = acc;
    }
    if (tid < 64) {
        float v = 0.f;
        for (int m = 0; m < 64; ++m) v = fmaf(glB[m], A[m * 64 + tid], v);
        vec[tid] = v;
    }
    __syncthreads();
    for (int kk = 0; kk < 16; ++kk) {
        int k = kq * 16 + kk;
        float acc = 0.f;
        for (int m = 0; m < 64; ++m) acc = fmaf(T[k * 64 + m], B[m * 64 + j], acc);
        Wff[k * 64 + j] = acc;
    }
    if (kq == 0) {
        float a = 0.f;
        for (int m = 0; m < 64; ++m) a = fmaf(vec[m], B[m * 64 + j], a);
        bff[j] = a;
    } else if (kq == 1) {
        float a = 0.f;
        for (int m = 0; m < 64; ++m) a = fmaf(glB[64 + m], B[m * 64 + j], a);
        bff[64 + j] = a;
    } else if (kq == 2) {
        bff[128 + j] = corrB[j];
    }
}

// ---------------------------------------------------------------------------
// k_proj: Cb[b] = gg[node]@Wff + s2[node]*bff1 + sdeg[node]*bff2 + corrB
// ---------------------------------------------------------------------------
__global__ __launch_bounds__(256) void k_proj(const float* __restrict__ gg,
                                              const float* __restrict__ sdeg,
                                              const float* __restrict__ s2,
                                              const int* __restrict__ users,
                                              const int* __restrict__ items,
                                              const float* __restrict__ Wff,
                                              const float* __restrict__ bff,
                                              float* __restrict__ Cb, int nb) {
    __shared__ float Ws[4096];
    __shared__ float xsh[16][64];
    __shared__ float ssh[16][2];
    int tid = threadIdx.x, j = tid & 63, rq = tid >> 6;
    for (int i = tid; i < 4096; i += 256) Ws[i] = Wff[i];
    int r0 = blockIdx.x * 16;
    for (int i = tid; i < 1024; i += 256) {
        int b = r0 + (i >> 6);
        int node = (b < nb) ? users[b] : (NU + items[b - nb]);
        xsh[i >> 6][i & 63] = gg[(size_t)node * 64 + (i & 63)];
    }
    if (tid < 16) {
        int b = r0 + tid;
        int node = (b < nb) ? users[b] : (NU + items[b - nb]);
        ssh[tid][0] = s2[node];
        ssh[tid][1] = sdeg[node];
    }
    __syncthreads();
    float b1j = bff[j], b2j = bff[64 + j], cbj = bff[128 + j];
    float acc[4];
#pragma unroll
    for (int i = 0; i < 4; ++i) acc[i] = cbj;
    for (int k = 0; k < 64; ++k) {
        float w = Ws[k * 64 + j];
#pragma unroll
        for (int i = 0; i < 4; ++i) acc[i] = fmaf(xsh[rq + 4 * i][k], w, acc[i]);
    }
#pragma unroll
    for (int i = 0; i < 4; ++i) {
        int r = rq + 4 * i;
        Cb[(size_t)(r0 + r) * 64 + j] = acc[i] + ssh[r][0] * b1j + ssh[r][1] * b2j;
    }
}

// ---------------------------------------------------------------------------
// k_attn: x = LN1(x + x @ W_va + b_va).  16 rows/block.
// ---------------------------------------------------------------------------
__global__ __launch_bounds__(256) void k_attn(float* __restrict__ Cb,
                                              const float* __restrict__ Wva,
                                              const float* __restrict__ bva,
                                              const float* __restrict__ g,
                                              const float* __restrict__ bt,
                                              int layer) {
    __shared__ float Ws[4096];
    __shared__ float xs[16][64];
    int tid = threadIdx.x, j = tid & 63, rq = tid >> 6;
    const float* wv = Wva + layer * 4096;
    for (int i = tid; i < 4096; i += 256) Ws[i] = wv[i];
    int row0 = blockIdx.x * 16;
    for (int i = tid; i < 1024; i += 256)
        xs[i >> 6][i & 63] = Cb[(size_t)(row0 + (i >> 6)) * 64 + (i & 63)];
    __syncthreads();
    float bv = bva[layer * 64 + j];
    float gg = g[layer * 64 + j], bb = bt[layer * 64 + j];
    float acc[4];
#pragma unroll
    for (int i = 0; i < 4; ++i) acc[i] = bv;
    for (int k = 0; k < 64; ++k) {
        float w = Ws[k * 64 + j];
#pragma unroll
        for (int i = 0; i < 4; ++i) acc[i] = fmaf(xs[rq * 4 + i][k], w, acc[i]);
    }
#pragma unroll
    for (int i = 0; i < 4; ++i) {
        int r = rq * 4 + i;
        float xv = xs[r][j] + acc[i];
        float s = xv;
#pragma unroll
        for (int o = 32; o >= 1; o >>= 1) s += __shfl_xor(s, o, 64);
        float m = s * (1.0f / 64.0f);
        float d = xv - m;
        float s2v = d * d;
#pragma unroll
        for (int o = 32; o >= 1; o >>= 1) s2v += __shfl_xor(s2v, o, 64);
        float xn = d * rsqrtf(s2v * (1.0f / 64.0f) + LNEPS) * gg + bb;
        Cb[(size_t)(row0 + r) * 64 + j] = xn;
    }
}

// ---------------------------------------------------------------------------
// k_ffn1: partial FFN.  Block (rt, hc): rows rt*32..+31, hidden hc*128..+127.
// ---------------------------------------------------------------------------
__global__ __launch_bounds__(256) void k_ffn1(const float* __restrict__ Cb,
                                              const float* __restrict__ ff1W,
                                              const float* __restrict__ ff1B,
                                              const float* __restrict__ ff2W,
                                              float* __restrict__ ypart,
                                              int layer, int nrows) {
    __shared__ float xs[32][64];
    __shared__ float ts[32][128];
    const float* w1 = ff1W + (size_t)layer * 64 * 2048;
    const float* w2 = ff2W + (size_t)layer * 2048 * 64;
    const float* b1 = ff1B + layer * 2048;
    int tid = threadIdx.x;
    int rt = blockIdx.x;
    int hc = blockIdx.y;
    int row0 = rt * 32;
    for (int i = tid; i < 32 * 64; i += 256)
        xs[i >> 6][i & 63] = Cb[(size_t)(row0 + (i >> 6)) * 64 + (i & 63)];
    __syncthreads();
    int hh = tid & 63;
    int rg = tid >> 6;
    int h0 = hc * 128 + hh;
    float ta[8], tb[8];
    float bba = b1[h0], bbb = b1[h0 + 64];
#pragma unroll
    for (int i = 0; i < 8; ++i) { ta[i] = bba; tb[i] = bbb; }
    for (int k = 0; k < 64; k += 4) {
        float4 xv[8];
#pragma unroll
        for (int i = 0; i < 8; ++i)
            xv[i] = *reinterpret_cast<const float4*>(&xs[rg * 8 + i][k]);
#pragma unroll
        for (int kk = 0; kk < 4; ++kk) {
            float w1a = w1[(size_t)(k + kk) * 2048 + h0];
            float w1b = w1[(size_t)(k + kk) * 2048 + h0 + 64];
#pragma unroll
            for (int i = 0; i < 8; ++i) {
                float xvk = (kk == 0) ? xv[i].x : (kk == 1) ? xv[i].y
                          : (kk == 2) ? xv[i].z : xv[i].w;
                ta[i] = fmaf(xvk, w1a, ta[i]);
                tb[i] = fmaf(xvk, w1b, tb[i]);
            }
        }
    }
#pragma unroll
    for (int i = 0; i < 8; ++i) {
        ts[rg * 8 + i][hh]      = fmaxf(ta[i], 0.f);
        ts[rg * 8 + i][hh + 64] = fmaxf(tb[i], 0.f);
    }
    __syncthreads();
    int j = hh;
    float ya[8];
#pragma unroll
    for (int i = 0; i < 8; ++i) ya[i] = 0.f;
    for (int m = 0; m < 128; ++m) {
        float w2v = w2[(size_t)(hc * 128 + m) * 64 + j];
#pragma unroll
        for (int i = 0; i < 8; ++i) ya[i] = fmaf(ts[rg * 8 + i][m], w2v, ya[i]);
    }
#pragma unroll
    for (int i = 0; i < 8; ++i)
        ypart[((size_t)hc * nrows + row0 + rg * 8 + i) * 64 + j] = ya[i];
}

// ---------------------------------------------------------------------------
// k_ffn2: y = sum_p ypart[p]; x = LN2(x + y + b2).  16 rows/block.
// ---------------------------------------------------------------------------
__global__ __launch_bounds__(256) void k_ffn2(float* __restrict__ Cb,
                                              const float* __restrict__ ypart,
                                              const float* __restrict__ ff2B,
                                              const float* __restrict__ g,
                                              const float* __restrict__ bt,
                                              int layer, int nrows) {
    int tid = threadIdx.x;
    int j = tid & 63, rq = tid >> 6;
    int row0 = blockIdx.x * 16;
    float b2 = ff2B[layer * 64 + j];
    float gg = g[layer * 64 + j], bb = bt[layer * 64 + j];
#pragma unroll
    for (int i = 0; i < 4; ++i) {
        int r = row0 + rq * 4 + i;
        float y = 0.f;
#pragma unroll
        for (int p = 0; p < 16; ++p)
            y += ypart[((size_t)p * nrows + r) * 64 + j];
        float xv = Cb[(size_t)r * 64 + j] + y + b2;
        float s = xv;
#pragma unroll
        for (int o = 32; o >= 1; o >>= 1) s += __shfl_xor(s, o, 64);
        float m = s * (1.0f / 64.0f);
        float d = xv - m;
        float s2v = d * d;
#pragma unroll
        for (int o = 32; o >= 1; o >>= 1) s2v += __shfl_xor(s2v, o, 64);
        float xn = d * rsqrtf(s2v * (1.0f / 64.0f) + LNEPS) * gg + bb;
        Cb[(size_t)r * 64 + j] = xn;
    }
}

// out[b] = dot(user_row b, item_row nb+b); quarter-wave per b.
__global__ __launch_bounds__(256) void k_dot(const float* __restrict__ Cb,
                                             float* __restrict__ out, int nb) {
    int t = blockIdx.x * 256 + threadIdx.x;
    int b = t >> 4;
    if (b >= nb) return;
    int q = (t & 15) * 4;
    const float4 u = *reinterpret_cast<const float4*>(Cb + (size_t)b * 64 + q);
    const float4 v = *reinterpret_cast<const float4*>(Cb + (size_t)(nb + b) * 64 + q);
    float s = u.x * v.x + u.y * v.y + u.z * v.z + u.w * v.w;
#pragma unroll
    for (int o = 8; o >= 1; o >>= 1) s += __shfl_xor(s, o, 16);
    if ((t & 15) == 0) out[b] = s;
}

extern "C" void kernel_launch(void* const* d_in, const int* in_sizes, int n_in,
                              void* d_out, int out_size, void* d_ws, size_t ws_size,
                              hipStream_t stream) {
    const int* users = (const int*)d_in[0];
    const int* items = (const int*)d_in[1];
    const int* ei    = (const int*)d_in[2];
    const float* ut  = (const float*)d_in[3];
    const float* itb = (const float*)d_in[4];
    const float* glW = (const float*)d_in[5];
    const float* glB = (const float*)d_in[6];
    const float* corrW = (const float*)d_in[7];
    const float* corrB = (const float*)d_in[8];
    const float* qkvW = (const float*)d_in[9];
    const float* qkvB = (const float*)d_in[10];
    const float* outW = (const float*)d_in[11];
    const float* outB = (const float*)d_in[12];
    const float* ff1W = (const float*)d_in[13];
    const float* ff1B = (const float*)d_in[14];
    const float* ff2W = (const float*)d_in[15];
    const float* ff2B = (const float*)d_in[16];
    const float* ln1g = (const float*)d_in[17];
    const float* ln1b = (const float*)d_in[18];
    const float* ln2g = (const float*)d_in[19];
    const float* ln2b = (const float*)d_in[20];

    const int E  = in_sizes[2] / 2;      // 1,750,000
    const int nb = in_sizes[0];          // 4096
    const int nrows = 2 * nb;            // 8192
    const int* rowp = ei;
    const int* colp = ei + E;

    // workspace carve-up (~96 MB)
    char* w = (char*)d_ws;
    size_t off = 0;
    auto alloc = [&](size_t bytes) {
        char* p = w + off;
        off += (bytes + 255) & ~(size_t)255;
        return p;
    };
    int*      deg   = (int*)alloc((size_t)NN * 4);
    float*    dis   = (float*)alloc((size_t)NN * 4);
    unsigned* bS    = (unsigned*)alloc(((NN + 31) / 32) * 4);
    unsigned* bR    = (unsigned*)alloc(((NN + 31) / 32) * 4);
    int*      cnt   = (int*)alloc((size_t)NNP * 4);
    int*      start = (int*)alloc((size_t)(NNP + 1) * 4);
    int*      cur   = (int*)alloc((size_t)NN * 4);
    int*      bsum  = (int*)alloc((size_t)SCNB * 4);
    int2*     el    = (int2*)alloc((size_t)E * 8);
    float*    bufA  = (float*)alloc((size_t)NN * 64 * 4);   // g1 (38.4 MB)
    float*    bufB  = (float*)alloc((size_t)NN * 64 * 4);   // gg
    float*    sdeg  = (float*)alloc((size_t)NN * 4);
    float*    s2    = (float*)alloc((size_t)NN * 4);
    float*    cb    = (float*)alloc((size_t)nrows * 64 * 4);
    float*    Wva   = (float*)alloc(2 * 4096 * 4);
    float*    bva   = (float*)alloc(2 * 64 * 4);
    float*    Wff   = (float*)alloc(4096 * 4);
    float*    bff   = (float*)alloc(192 * 4);
    float*    outp  = (float*)d_out;
    float*    ypart = bufA;   // 33.5 MB overlay; bufA (g1) dead after k_gather2

    hipMemsetAsync(deg, 0, (size_t)NN * 4, stream);
    hipMemsetAsync(bS, 0, ((NN + 31) / 32) * 4, stream);
    hipMemsetAsync(bR, 0, ((NN + 31) / 32) * 4, stream);
    hipMemsetAsync(cnt, 0, (size_t)NNP * 4, stream);
    hipMemsetAsync(cur, 0, (size_t)NN * 4, stream);

    int eb = (E + 255) / 256;
    int nnb = (NN + 255) / 256;

    // --- CSR build (edges with col in R) ---
    k_markS<<<(2 * nb + 255) / 256, 256, 0, stream>>>(users, items, bS, nb);
    k_pre1<<<eb, 256, 0, stream>>>(rowp, colp, bS, deg, bR, E);
    k_dis<<<nnb, 256, 0, stream>>>(deg, dis);
    k_cnt<<<eb, 256, 0, stream>>>(colp, bR, cnt, E);
    k_scan1<<<SCNB, 256, 0, stream>>>(cnt, bsum);
    k_scan2<<<1, 256, 0, stream>>>(bsum, SCNB);
    k_scan3<<<SCNB, 256, 0, stream>>>(cnt, bsum, start);
    k_place<<<eb, 256, 0, stream>>>(rowp, colp, bR, dis, start, cur, el, E);
    k_fuse<<<2, 256, 0, stream>>>(qkvW, qkvB, outW, outB, Wva, bva);
    k_fuse2<<<1, 256, 0, stream>>>(glW, glB, corrW, corrB, Wff, bff);

    int agb = (NN + 3) / 4;    // 4 waves/block, 1 wave per col

    // commuted GCN: gather raw tables (R cols), gather again (S cols),
    // then one fused 8K-row projection
    k_gather1<<<agb, 256, 0, stream>>>(el, start, ut, itb, bufA, sdeg);
    k_gather2<<<agb, 256, 0, stream>>>(el, start, bufA, sdeg, bS, bufB, s2);
    k_proj<<<(nrows + 15) / 16, 256, 0, stream>>>(bufB, sdeg, s2, users, items,
                                                  Wff, bff, cb, nb);

    // transformer: per layer  attn+LN1 -> partial FFN -> reduce+LN2
    dim3 fgrid(nrows / 32, 16);
    for (int l = 0; l < 2; ++l) {
        k_attn<<<nrows / 16, 256, 0, stream>>>(cb, Wva, bva, ln1g, ln1b, l);
        k_ffn1<<<fgrid, 256, 0, stream>>>(cb, ff1W, ff1B, ff2W, ypart, l, nrows);
        k_ffn2<<<nrows / 16, 256, 0, stream>>>(cb, ypart, ff2B, ln2g, ln2b, l, nrows);
    }
    k_dot<<<(nb * 16 + 255) / 256, 256, 0, stream>>>(cb, outp, nb);
}

// Round 7
// 507.433 us; speedup vs baseline: 6.6927x; 1.1652x over previous
//
#include <hip/hip_runtime.h>
#include <math.h>

// Problem constants (fixed by the reference's setup_inputs)
#define NU 100000
#define NI 50000
#define NN 150000          // NU + NI
#define NNP 150528         // NN padded to 147*1024 for the scan
#define SCNB 147           // scan blocks (1024 elems each)
#define LNEPS 1e-5f

typedef short bfx8 __attribute__((ext_vector_type(8)));
typedef float f32x4 __attribute__((ext_vector_type(4)));
#define MFMA16(a, b, c) __builtin_amdgcn_mfma_f32_16x16x32_bf16(a, b, c, 0, 0, 0)

__device__ __forceinline__ unsigned short f2bf(float f) {
    unsigned u = __float_as_uint(f);
    unsigned r = u + 0x7FFFu + ((u >> 16) & 1u);   // RNE
    return (unsigned short)(r >> 16);
}

// ---------------------------------------------------------------------------
// Bitmaps: S = sampled nodes; R = rows of edges whose col is in S.
// ---------------------------------------------------------------------------
__global__ __launch_bounds__(256) void k_markS(const int* __restrict__ users,
                                               const int* __restrict__ items,
                                               unsigned* __restrict__ bS, int nb) {
    int t = blockIdx.x * 256 + threadIdx.x;
    if (t < 2 * nb) {
        int node = (t < nb) ? users[t] : (NU + items[t - nb]);
        atomicOr(&bS[node >> 5], 1u << (node & 31));
    }
}

// deg (out-degree over row, int) + markR in one edge pass.
__global__ __launch_bounds__(256) void k_pre1(const int* __restrict__ row,
                                              const int* __restrict__ col,
                                              const unsigned* __restrict__ bS,
                                              int* __restrict__ deg,
                                              unsigned* __restrict__ bR, int E) {
    int e = blockIdx.x * 256 + threadIdx.x;
    if (e >= E) return;
    int r = row[e];
    atomicAdd(&deg[r], 1);
    int c = col[e];
    if ((bS[c >> 5] >> (c & 31)) & 1u) atomicOr(&bR[r >> 5], 1u << (r & 31));
}

__global__ __launch_bounds__(256) void k_dis(const int* __restrict__ deg,
                                             float* __restrict__ dis) {
    int i = blockIdx.x * 256 + threadIdx.x;
    if (i < NN) dis[i] = rsqrtf((float)deg[i]);
}

// count edges per col, only for cols in R
__global__ __launch_bounds__(256) void k_cnt(const int* __restrict__ col,
                                             const unsigned* __restrict__ bR,
                                             int* __restrict__ cnt, int E) {
    int e = blockIdx.x * 256 + threadIdx.x;
    if (e >= E) return;
    int c = col[e];
    if ((bR[c >> 5] >> (c & 31)) & 1u) atomicAdd(&cnt[c], 1);
}

// ---------------------------------------------------------------------------
// Exclusive scan of cnt[NNP] -> start[NNP+1]
// ---------------------------------------------------------------------------
__global__ __launch_bounds__(256) void k_scan1(const int* __restrict__ cnt,
                                               int* __restrict__ bsum) {
    __shared__ int sh[256];
    int b = blockIdx.x, t = threadIdx.x;
    int4 v = ((const int4*)cnt)[b * 256 + t];
    sh[t] = v.x + v.y + v.z + v.w;
    __syncthreads();
    for (int off = 128; off >= 1; off >>= 1) {
        if (t < off) sh[t] += sh[t + off];
        __syncthreads();
    }
    if (t == 0) bsum[b] = sh[0];
}

// wave-parallel exclusive scan of the 147 block sums (single block)
__global__ __launch_bounds__(256) void k_scan2(int* __restrict__ bsum, int nblk) {
    __shared__ int sh[256];
    int t = threadIdx.x;
    int v = (t < nblk) ? bsum[t] : 0;
    sh[t] = v;
    __syncthreads();
    for (int off = 1; off < 256; off <<= 1) {
        int add = (t >= off) ? sh[t - off] : 0;
        __syncthreads();
        sh[t] += add;
        __syncthreads();
    }
    if (t < nblk) bsum[t] = sh[t] - v;   // exclusive
}

__global__ __launch_bounds__(256) void k_scan3(const int* __restrict__ cnt,
                                               const int* __restrict__ bsum,
                                               int* __restrict__ start) {
    __shared__ int sh[257];
    int b = blockIdx.x, t = threadIdx.x;
    int4 v = ((const int4*)cnt)[b * 256 + t];
    int s = v.x + v.y + v.z + v.w;
    sh[t + 1] = s;
    if (t == 0) sh[0] = 0;
    __syncthreads();
    for (int off = 1; off < 256; off <<= 1) {
        int add = sh[t + 1] + ((t + 1 > off) ? sh[t + 1 - off] : 0);
        __syncthreads();
        sh[t + 1] = add;
        __syncthreads();
    }
    int base = bsum[b] + sh[t];
    int i0 = b * 1024 + t * 4;
    start[i0 + 0] = base;  base += v.x;
    start[i0 + 1] = base;  base += v.y;
    start[i0 + 2] = base;  base += v.z;
    start[i0 + 3] = base;
    if (b == SCNB - 1 && t == 255) start[NNP] = base + v.w;
}

// place packed {row, nrm} into CSR slots (order within a col is arbitrary)
__global__ __launch_bounds__(256) void k_place(const int* __restrict__ row,
                                               const int* __restrict__ col,
                                               const unsigned* __restrict__ bR,
                                               const float* __restrict__ dis,
                                               const int* __restrict__ start,
                                               int* __restrict__ cur,
                                               int2* __restrict__ el, int E) {
    int e = blockIdx.x * 256 + threadIdx.x;
    if (e >= E) return;
    int c = col[e];
    if (!((bR[c >> 5] >> (c & 31)) & 1u)) return;
    int r = row[e];
    float nv = dis[r] * dis[c];
    int pos = atomicAdd(&cur[c], 1);
    el[start[c] + pos] = make_int2(r, __float_as_int(nv));
}

// ---------------------------------------------------------------------------
// gather1: g1[c] = sum nrm * x_raw[row];  sdeg[c] = sum nrm.   cols in R.
// ---------------------------------------------------------------------------
__global__ __launch_bounds__(256) void k_gather1(const int2* __restrict__ el,
                                                 const int* __restrict__ start,
                                                 const float* __restrict__ ut,
                                                 const float* __restrict__ itb,
                                                 float* __restrict__ g1,
                                                 float* __restrict__ sdeg) {
    int wid = (blockIdx.x * 256 + threadIdx.x) >> 6;
    int j = threadIdx.x & 63;
    if (wid >= NN) return;
    int s = start[wid], e = start[wid + 1];
    if (s == e) return;
    float acc0 = 0.f, acc1 = 0.f, sn = 0.f;
    int i = s;
    for (; i + 1 < e; i += 2) {
        int2 e0 = el[i], e1 = el[i + 1];
        float n0 = __int_as_float(e0.y), n1 = __int_as_float(e1.y);
        const float* s0 = (e0.x < NU) ? ut + (size_t)e0.x * 64
                                      : itb + (size_t)(e0.x - NU) * 64;
        const float* s1 = (e1.x < NU) ? ut + (size_t)e1.x * 64
                                      : itb + (size_t)(e1.x - NU) * 64;
        acc0 = fmaf(n0, s0[j], acc0);
        acc1 = fmaf(n1, s1[j], acc1);
        sn += n0 + n1;
    }
    if (i < e) {
        int2 e0 = el[i];
        float n0 = __int_as_float(e0.y);
        const float* s0 = (e0.x < NU) ? ut + (size_t)e0.x * 64
                                      : itb + (size_t)(e0.x - NU) * 64;
        acc0 = fmaf(n0, s0[j], acc0);
        sn += n0;
    }
    g1[(size_t)wid * 64 + j] = acc0 + acc1;
    if (j == 0) sdeg[wid] = sn;
}

// ---------------------------------------------------------------------------
// gather2: gg[c] = sum nrm * g1[row];  s2[c] = sum nrm * sdeg[row].  cols in S.
// ---------------------------------------------------------------------------
__global__ __launch_bounds__(256) void k_gather2(const int2* __restrict__ el,
                                                 const int* __restrict__ start,
                                                 const float* __restrict__ g1,
                                                 const float* __restrict__ sdeg,
                                                 const unsigned* __restrict__ bS,
                                                 float* __restrict__ gg,
                                                 float* __restrict__ s2) {
    int wid = (blockIdx.x * 256 + threadIdx.x) >> 6;
    int j = threadIdx.x & 63;
    if (wid >= NN) return;
    if (!((bS[wid >> 5] >> (wid & 31)) & 1u)) return;
    int s = start[wid], e = start[wid + 1];
    float acc0 = 0.f, acc1 = 0.f, sa = 0.f;
    int i = s;
    for (; i + 1 < e; i += 2) {
        int2 e0 = el[i], e1 = el[i + 1];
        float n0 = __int_as_float(e0.y), n1 = __int_as_float(e1.y);
        acc0 = fmaf(n0, g1[(size_t)e0.x * 64 + j], acc0);
        acc1 = fmaf(n1, g1[(size_t)e1.x * 64 + j], acc1);
        sa = fmaf(n0, sdeg[e0.x], sa);
        sa = fmaf(n1, sdeg[e1.x], sa);
    }
    if (i < e) {
        int2 e0 = el[i];
        float n0 = __int_as_float(e0.y);
        acc0 = fmaf(n0, g1[(size_t)e0.x * 64 + j], acc0);
        sa = fmaf(n0, sdeg[e0.x], sa);
    }
    gg[(size_t)wid * 64 + j] = acc0 + acc1;
    if (j == 0) s2[wid] = sa;
}

// ---------------------------------------------------------------------------
// k_fuse: W_va[l] = Wv[l] @ Wo[l];  b_va[l] = bv[l] @ Wo[l] + bo[l]
// ---------------------------------------------------------------------------
__global__ __launch_bounds__(256) void k_fuse(const float* __restrict__ qkvW,
                                              const float* __restrict__ qkvB,
                                              const float* __restrict__ outW,
                                              const float* __restrict__ outB,
                                              float* __restrict__ Wva,
                                              float* __restrict__ bva) {
    int l = blockIdx.x;
    __shared__ float wo[4096];
    int tid = threadIdx.x, j = tid & 63, kq = tid >> 6;
    for (int i = tid; i < 4096; i += 256) wo[i] = outW[l * 4096 + i];
    __syncthreads();
    for (int kk = 0; kk < 16; ++kk) {
        int k = kq * 16 + kk;
        float acc = 0.f;
        for (int m = 0; m < 64; ++m)
            acc = fmaf(qkvW[(size_t)l * 64 * 192 + k * 192 + 128 + m],
                       wo[m * 64 + j], acc);
        Wva[l * 4096 + k * 64 + j] = acc;
    }
    if (tid < 64) {
        float acc = outB[l * 64 + j];
        for (int m = 0; m < 64; ++m)
            acc = fmaf(qkvB[l * 192 + 128 + m], wo[m * 64 + j], acc);
        bva[l * 64 + j] = acc;
    }
}

// ---------------------------------------------------------------------------
// k_fuse2: Wff = W0@W1@corrW; bff = [b0@W1@corrW, b1@corrW, corrB]
// ---------------------------------------------------------------------------
__global__ __launch_bounds__(256) void k_fuse2(const float* __restrict__ glW,
                                               const float* __restrict__ glB,
                                               const float* __restrict__ corrW,
                                               const float* __restrict__ corrB,
                                               float* __restrict__ Wff,
                                               float* __restrict__ bff) {
    __shared__ float A[4096];   // W1
    __shared__ float B[4096];   // corrW
    __shared__ float T[4096];   // W0@W1
    __shared__ float vec[64];
    int tid = threadIdx.x, j = tid & 63, kq = tid >> 6;
    for (int i = tid; i < 4096; i += 256) { A[i] = glW[4096 + i]; B[i] = corrW[i]; }
    __syncthreads();
    for (int kk = 0; kk < 16; ++kk) {
        int k = kq * 16 + kk;
        float acc = 0.f;
        for (int m = 0; m < 64; ++m) acc = fmaf(glW[k * 64 + m], A[m * 64 + j], acc);
        T[k * 64 + j] = acc;
    }
    if (tid < 64) {
        float v = 0.f;
        for (int m = 0; m < 64; ++m) v = fmaf(glB[m], A[m * 64 + tid], v);
        vec[tid] = v;
    }
    __syncthreads();
    for (int kk = 0; kk < 16; ++kk) {
        int k = kq * 16 + kk;
        float acc = 0.f;
        for (int m = 0; m < 64; ++m) acc = fmaf(T[k * 64 + m], B[m * 64 + j], acc);
        Wff[k * 64 + j] = acc;
    }
    if (kq == 0) {
        float a = 0.f;
        for (int m = 0; m < 64; ++m) a = fmaf(vec[m], B[m * 64 + j], a);
        bff[j] = a;
    } else if (kq == 1) {
        float a = 0.f;
        for (int m = 0; m < 64; ++m) a = fmaf(glB[64 + m], B[m * 64 + j], a);
        bff[64 + j] = a;
    } else if (kq == 2) {
        bff[128 + j] = corrB[j];
    }
}

// ---------------------------------------------------------------------------
// k_wprep: transpose+convert FFN weights to bf16.
// Wt1[l][h][k] = ff1W[l][k][h]   (2048x64 per layer)
// Wt2[l][j][m] = ff2W[l][m][j]   (64x2048 per layer)
// ---------------------------------------------------------------------------
__global__ __launch_bounds__(256) void k_wprep(const float* __restrict__ ff1W,
                                               const float* __restrict__ ff2W,
                                               unsigned short* __restrict__ Wt1,
                                               unsigned short* __restrict__ Wt2) {
    __shared__ float sh[64][65];
    int b = blockIdx.x;          // 0..127
    int l = b >> 6, rem = b & 63;
    int mat = rem >> 5, tile = rem & 31;
    const float* src; unsigned short* dst; int C, R, r0, c0;
    if (mat == 0) { src = ff1W + (size_t)l * 64 * 2048; dst = Wt1 + (size_t)l * 2048 * 64;
                    R = 64; C = 2048; r0 = 0; c0 = tile * 64; }
    else          { src = ff2W + (size_t)l * 2048 * 64; dst = Wt2 + (size_t)l * 64 * 2048;
                    R = 2048; C = 64; r0 = tile * 64; c0 = 0; }
    int tid = threadIdx.x;
    for (int it = 0; it < 16; ++it) {
        int idx = it * 256 + tid;
        int lr = idx >> 6, lc = idx & 63;
        sh[lr][lc] = src[(size_t)(r0 + lr) * C + (c0 + lc)];
    }
    __syncthreads();
    for (int it = 0; it < 16; ++it) {
        int idx = it * 256 + tid;
        int lc = idx >> 6, lr = idx & 63;
        dst[(size_t)(c0 + lc) * R + (r0 + lr)] = f2bf(sh[lr][lc]);
    }
}

// ---------------------------------------------------------------------------
// k_proj: Cb[b] = gg[node]@Wff + s2[node]*bff1 + sdeg[node]*bff2 + corrB
// ---------------------------------------------------------------------------
__global__ __launch_bounds__(256) void k_proj(const float* __restrict__ gg,
                                              const float* __restrict__ sdeg,
                                              const float* __restrict__ s2,
                                              const int* __restrict__ users,
                                              const int* __restrict__ items,
                                              const float* __restrict__ Wff,
                                              const float* __restrict__ bff,
                                              float* __restrict__ Cb, int nb) {
    __shared__ float Ws[4096];
    __shared__ float xsh[16][64];
    __shared__ float ssh[16][2];
    int tid = threadIdx.x, j = tid & 63, rq = tid >> 6;
    for (int i = tid; i < 4096; i += 256) Ws[i] = Wff[i];
    int r0 = blockIdx.x * 16;
    for (int i = tid; i < 1024; i += 256) {
        int b = r0 + (i >> 6);
        int node = (b < nb) ? users[b] : (NU + items[b - nb]);
        xsh[i >> 6][i & 63] = gg[(size_t)node * 64 + (i & 63)];
    }
    if (tid < 16) {
        int b = r0 + tid;
        int node = (b < nb) ? users[b] : (NU + items[b - nb]);
        ssh[tid][0] = s2[node];
        ssh[tid][1] = sdeg[node];
    }
    __syncthreads();
    float b1j = bff[j], b2j = bff[64 + j], cbj = bff[128 + j];
    float acc[4];
#pragma unroll
    for (int i = 0; i < 4; ++i) acc[i] = cbj;
    for (int k = 0; k < 64; ++k) {
        float w = Ws[k * 64 + j];
#pragma unroll
        for (int i = 0; i < 4; ++i) acc[i] = fmaf(xsh[rq + 4 * i][k], w, acc[i]);
    }
#pragma unroll
    for (int i = 0; i < 4; ++i) {
        int r = rq + 4 * i;
        Cb[(size_t)(r0 + r) * 64 + j] = acc[i] + ssh[r][0] * b1j + ssh[r][1] * b2j;
    }
}

// ---------------------------------------------------------------------------
// k_attn: x = LN1(x + x @ W_va + b_va).  Writes fp32 Cb and bf16 xb.
// ---------------------------------------------------------------------------
__global__ __launch_bounds__(256) void k_attn(float* __restrict__ Cb,
                                              unsigned short* __restrict__ xb,
                                              const float* __restrict__ Wva,
                                              const float* __restrict__ bva,
                                              const float* __restrict__ g,
                                              const float* __restrict__ bt,
                                              int layer) {
    __shared__ float Ws[4096];
    __shared__ float xs[16][64];
    int tid = threadIdx.x, j = tid & 63, rq = tid >> 6;
    const float* wv = Wva + layer * 4096;
    for (int i = tid; i < 4096; i += 256) Ws[i] = wv[i];
    int row0 = blockIdx.x * 16;
    for (int i = tid; i < 1024; i += 256)
        xs[i >> 6][i & 63] = Cb[(size_t)(row0 + (i >> 6)) * 64 + (i & 63)];
    __syncthreads();
    float bv = bva[layer * 64 + j];
    float gg = g[layer * 64 + j], bb = bt[layer * 64 + j];
    float acc[4];
#pragma unroll
    for (int i = 0; i < 4; ++i) acc[i] = bv;
    for (int k = 0; k < 64; ++k) {
        float w = Ws[k * 64 + j];
#pragma unroll
        for (int i = 0; i < 4; ++i) acc[i] = fmaf(xs[rq * 4 + i][k], w, acc[i]);
    }
#pragma unroll
    for (int i = 0; i < 4; ++i) {
        int r = rq * 4 + i;
        float xv = xs[r][j] + acc[i];
        float s = xv;
#pragma unroll
        for (int o = 32; o >= 1; o >>= 1) s += __shfl_xor(s, o, 64);
        float m = s * (1.0f / 64.0f);
        float d = xv - m;
        float s2v = d * d;
#pragma unroll
        for (int o = 32; o >= 1; o >>= 1) s2v += __shfl_xor(s2v, o, 64);
        float xn = d * rsqrtf(s2v * (1.0f / 64.0f) + LNEPS) * gg + bb;
        Cb[(size_t)(row0 + r) * 64 + j] = xn;
        xb[(size_t)(row0 + r) * 64 + j] = f2bf(xn);
    }
}

// ---------------------------------------------------------------------------
// k_ffnm: full FFN via MFMA + fused residual + LN2.
// Block: 32 rows, 512 threads (8 waves).  Loop over 16 hidden chunks of 128.
//   phase1 (per wave, 16-hidden slice): t = relu(x@W1c + b1) -> swizzled LDS
//   phase2 (wave (mh,nt2)): y[16 rows][16 cols] += t@W2c   (2 alt accums)
// Then ys -> residual + LN2 -> Cb.
// A/B frags both use k-map "8 contiguous at 8*(lane>>4)" -> k-permutation
// cancels; only the HW-verified C/D layout matters.
// ---------------------------------------------------------------------------
__global__ __launch_bounds__(512) void k_ffnm(float* __restrict__ Cb,
                                              const unsigned short* __restrict__ xb,
                                              const unsigned short* __restrict__ Wt1,
                                              const unsigned short* __restrict__ Wt2,
                                              const float* __restrict__ ff1B,
                                              const float* __restrict__ ff2B,
                                              const float* __restrict__ g2,
                                              const float* __restrict__ b2t,
                                              int layer) {
    __shared__ short ts[32 * 128];   // bf16 t tile, XOR-swizzled (8KB)
    __shared__ float ys[32 * 64];    // fp32 y (8KB)
    const unsigned short* w1 = Wt1 + (size_t)layer * 2048 * 64;
    const unsigned short* w2 = Wt2 + (size_t)layer * 64 * 2048;
    const float* b1 = ff1B + layer * 2048;
    int tid = threadIdx.x;
    int lane = tid & 63, wv = tid >> 6;
    int g = lane >> 4, r16 = lane & 15;
    int row0 = blockIdx.x * 32;
    int nt2 = wv & 3, mh = wv >> 2;

    // x A-frags, loaded once: x[row0+16*mt+r16][32*ks+8*g ..+7]
    bfx8 ax[2][2];
#pragma unroll
    for (int mt = 0; mt < 2; ++mt)
#pragma unroll
        for (int ks = 0; ks < 2; ++ks)
            ax[mt][ks] = *(const bfx8*)(xb + ((size_t)(row0 + 16 * mt + r16)) * 64
                                        + 32 * ks + 8 * g);

    f32x4 yfA = {0.f, 0.f, 0.f, 0.f}, yfB = {0.f, 0.f, 0.f, 0.f};

    for (int hc = 0; hc < 16; ++hc) {
        // ---- phase 1: this wave's 16-hidden slice ----
        int h = hc * 128 + wv * 16 + r16;
        float b1v = b1[h];
        f32x4 tf0 = {b1v, b1v, b1v, b1v}, tf1 = tf0;
#pragma unroll
        for (int ks = 0; ks < 2; ++ks) {
            bfx8 bw = *(const bfx8*)(w1 + (size_t)h * 64 + 32 * ks + 8 * g);
            tf0 = MFMA16(ax[0][ks], bw, tf0);
            tf1 = MFMA16(ax[1][ks], bw, tf1);
        }
        // relu -> bf16 -> swizzled LDS.  lane holds t[4g+r (+16)][wv*16+r16]
        int col = wv * 16 + r16;
#pragma unroll
        for (int r = 0; r < 4; ++r) {
            int rowA = 4 * g + r, rowB = 16 + 4 * g + r;
            int offA = (rowA * 256 + col * 2) ^ ((rowA & 7) << 4);
            int offB = (rowB * 256 + col * 2) ^ ((rowB & 7) << 4);
            *(short*)((char*)ts + offA) = (short)f2bf(fmaxf(tf0[r], 0.f));
            *(short*)((char*)ts + offB) = (short)f2bf(fmaxf(tf1[r], 0.f));
        }
        __syncthreads();
        // ---- phase 2: y[16*mh..][16*nt2..] += t @ W2c ----
        int trow = 16 * mh + r16;
#pragma unroll
        for (int ks2 = 0; ks2 < 4; ++ks2) {
            int kl = 32 * ks2 + 8 * g;
            int off = (trow * 256 + kl * 2) ^ ((trow & 7) << 4);
            bfx8 ta = *(const bfx8*)((char*)ts + off);
            bfx8 bw2 = *(const bfx8*)(w2 + ((size_t)(16 * nt2 + r16)) * 2048
                                      + hc * 128 + kl);
            if (ks2 & 1) yfB = MFMA16(ta, bw2, yfB);
            else         yfA = MFMA16(ta, bw2, yfA);
        }
        __syncthreads();
    }
    // y frags -> ys
#pragma unroll
    for (int r = 0; r < 4; ++r)
        ys[(16 * mh + 4 * g + r) * 64 + 16 * nt2 + r16] = yfA[r] + yfB[r];
    __syncthreads();
    // residual + LN2: wave wv handles rows wv*4 .. +3, lane = col
    float b2 = ff2B[layer * 64 + lane];
    float gg = g2[layer * 64 + lane], bb = b2t[layer * 64 + lane];
#pragma unroll
    for (int i = 0; i < 4; ++i) {
        int r = wv * 4 + i;
        float xv = Cb[(size_t)(row0 + r) * 64 + lane] + ys[r * 64 + lane] + b2;
        float s = xv;
#pragma unroll
        for (int o = 32; o >= 1; o >>= 1) s += __shfl_xor(s, o, 64);
        float m = s * (1.0f / 64.0f);
        float d = xv - m;
        float s2v = d * d;
#pragma unroll
        for (int o = 32; o >= 1; o >>= 1) s2v += __shfl_xor(s2v, o, 64);
        float xn = d * rsqrtf(s2v * (1.0f / 64.0f) + LNEPS) * gg + bb;
        Cb[(size_t)(row0 + r) * 64 + lane] = xn;
    }
}

// out[b] = dot(user_row b, item_row nb+b); quarter-wave per b.
__global__ __launch_bounds__(256) void k_dot(const float* __restrict__ Cb,
                                             float* __restrict__ out, int nb) {
    int t = blockIdx.x * 256 + threadIdx.x;
    int b = t >> 4;
    if (b >= nb) return;
    int q = (t & 15) * 4;
    const float4 u = *reinterpret_cast<const float4*>(Cb + (size_t)b * 64 + q);
    const float4 v = *reinterpret_cast<const float4*>(Cb + (size_t)(nb + b) * 64 + q);
    float s = u.x * v.x + u.y * v.y + u.z * v.z + u.w * v.w;
#pragma unroll
    for (int o = 8; o >= 1; o >>= 1) s += __shfl_xor(s, o, 16);
    if ((t & 15) == 0) out[b] = s;
}

extern "C" void kernel_launch(void* const* d_in, const int* in_sizes, int n_in,
                              void* d_out, int out_size, void* d_ws, size_t ws_size,
                              hipStream_t stream) {
    const int* users = (const int*)d_in[0];
    const int* items = (const int*)d_in[1];
    const int* ei    = (const int*)d_in[2];
    const float* ut  = (const float*)d_in[3];
    const float* itb = (const float*)d_in[4];
    const float* glW = (const float*)d_in[5];
    const float* glB = (const float*)d_in[6];
    const float* corrW = (const float*)d_in[7];
    const float* corrB = (const float*)d_in[8];
    const float* qkvW = (const float*)d_in[9];
    const float* qkvB = (const float*)d_in[10];
    const float* outW = (const float*)d_in[11];
    const float* outB = (const float*)d_in[12];
    const float* ff1W = (const float*)d_in[13];
    const float* ff1B = (const float*)d_in[14];
    const float* ff2W = (const float*)d_in[15];
    const float* ff2B = (const float*)d_in[16];
    const float* ln1g = (const float*)d_in[17];
    const float* ln1b = (const float*)d_in[18];
    const float* ln2g = (const float*)d_in[19];
    const float* ln2b = (const float*)d_in[20];

    const int E  = in_sizes[2] / 2;      // 1,750,000
    const int nb = in_sizes[0];          // 4096
    const int nrows = 2 * nb;            // 8192
    const int* rowp = ei;
    const int* colp = ei + E;

    // workspace carve-up (~98 MB)
    char* w = (char*)d_ws;
    size_t off = 0;
    auto alloc = [&](size_t bytes) {
        char* p = w + off;
        off += (bytes + 255) & ~(size_t)255;
        return p;
    };
    int*      deg   = (int*)alloc((size_t)NN * 4);
    float*    dis   = (float*)alloc((size_t)NN * 4);
    unsigned* bS    = (unsigned*)alloc(((NN + 31) / 32) * 4);
    unsigned* bR    = (unsigned*)alloc(((NN + 31) / 32) * 4);
    int*      cnt   = (int*)alloc((size_t)NNP * 4);
    int*      start = (int*)alloc((size_t)(NNP + 1) * 4);
    int*      cur   = (int*)alloc((size_t)NN * 4);
    int*      bsum  = (int*)alloc((size_t)SCNB * 4);
    int2*     el    = (int2*)alloc((size_t)E * 8);
    float*    bufA  = (float*)alloc((size_t)NN * 64 * 4);   // g1 (38.4 MB)
    float*    bufB  = (float*)alloc((size_t)NN * 64 * 4);   // gg
    float*    sdeg  = (float*)alloc((size_t)NN * 4);
    float*    s2    = (float*)alloc((size_t)NN * 4);
    float*    cb    = (float*)alloc((size_t)nrows * 64 * 4);
    float*    Wva   = (float*)alloc(2 * 4096 * 4);
    float*    bva   = (float*)alloc(2 * 64 * 4);
    float*    Wff   = (float*)alloc(4096 * 4);
    float*    bff   = (float*)alloc(192 * 4);
    unsigned short* xbb = (unsigned short*)alloc((size_t)nrows * 64 * 2);
    unsigned short* Wt1 = (unsigned short*)alloc((size_t)2 * 2048 * 64 * 2);
    unsigned short* Wt2 = (unsigned short*)alloc((size_t)2 * 64 * 2048 * 2);
    float*    outp  = (float*)d_out;

    hipMemsetAsync(deg, 0, (size_t)NN * 4, stream);
    hipMemsetAsync(bS, 0, ((NN + 31) / 32) * 4, stream);
    hipMemsetAsync(bR, 0, ((NN + 31) / 32) * 4, stream);
    hipMemsetAsync(cnt, 0, (size_t)NNP * 4, stream);
    hipMemsetAsync(cur, 0, (size_t)NN * 4, stream);

    int eb = (E + 255) / 256;
    int nnb = (NN + 255) / 256;

    // --- CSR build (edges with col in R) ---
    k_markS<<<(2 * nb + 255) / 256, 256, 0, stream>>>(users, items, bS, nb);
    k_pre1<<<eb, 256, 0, stream>>>(rowp, colp, bS, deg, bR, E);
    k_dis<<<nnb, 256, 0, stream>>>(deg, dis);
    k_cnt<<<eb, 256, 0, stream>>>(colp, bR, cnt, E);
    k_scan1<<<SCNB, 256, 0, stream>>>(cnt, bsum);
    k_scan2<<<1, 256, 0, stream>>>(bsum, SCNB);
    k_scan3<<<SCNB, 256, 0, stream>>>(cnt, bsum, start);
    k_place<<<eb, 256, 0, stream>>>(rowp, colp, bR, dis, start, cur, el, E);
    k_fuse<<<2, 256, 0, stream>>>(qkvW, qkvB, outW, outB, Wva, bva);
    k_fuse2<<<1, 256, 0, stream>>>(glW, glB, corrW, corrB, Wff, bff);
    k_wprep<<<128, 256, 0, stream>>>(ff1W, ff2W, Wt1, Wt2);

    int agb = (NN + 3) / 4;    // 4 waves/block, 1 wave per col

    // commuted GCN: gather raw tables (R cols), gather again (S cols),
    // then one fused 8K-row projection
    k_gather1<<<agb, 256, 0, stream>>>(el, start, ut, itb, bufA, sdeg);
    k_gather2<<<agb, 256, 0, stream>>>(el, start, bufA, sdeg, bS, bufB, s2);
    k_proj<<<(nrows + 15) / 16, 256, 0, stream>>>(bufB, sdeg, s2, users, items,
                                                  Wff, bff, cb, nb);

    // transformer: per layer  attn+LN1 (emits bf16 x) -> MFMA FFN + LN2
    for (int l = 0; l < 2; ++l) {
        k_attn<<<nrows / 16, 256, 0, stream>>>(cb, xbb, Wva, bva, ln1g, ln1b, l);
        k_ffnm<<<nrows / 32, 512, 0, stream>>>(cb, xbb, Wt1, Wt2, ff1B, ff2B,
                                               ln2g, ln2b, l);
    }
    k_dot<<<(nb * 16 + 255) / 256, 256, 0, stream>>>(cb, outp, nb);
}